// Round 9
// baseline (744.991 us; speedup 1.0000x reference)
//
#include <hip/hip_runtime.h>
#include <math.h>

// Problem constants
#define NI 8
#define NP 32
#define TOPK 3

typedef _Float16 f16;
typedef f16 f16x8 __attribute__((ext_vector_type(8)));
typedef f16 f16x4 __attribute__((ext_vector_type(4)));
typedef float f32x4 __attribute__((ext_vector_type(4)));

__device__ __forceinline__ float wave_sum(float v) {
  #pragma unroll
  for (int off = 32; off; off >>= 1) v += __shfl_xor(v, off);
  return v;
}

// async 16B global -> LDS (dest = wave-uniform base + lane*16)
__device__ __forceinline__ void gload16(const void* g, void* l) {
  __builtin_amdgcn_global_load_lds(
      (const __attribute__((address_space(1))) unsigned int*)g,
      (__attribute__((address_space(3))) unsigned int*)l, 16, 0, 0);
}

__device__ __forceinline__ void split4(float4 v, f16x4& h, f16x4& l) {
  h[0] = (f16)v.x; l[0] = (f16)(v.x - (float)h[0]);
  h[1] = (f16)v.y; l[1] = (f16)(v.y - (float)h[1]);
  h[2] = (f16)v.z; l[2] = (f16)(v.z - (float)h[2]);
  h[3] = (f16)v.w; l[3] = (f16)(v.w - (float)h[3]);
}

// pack one fp32 into (hi f16 | lo f16 << 16)
__device__ __forceinline__ unsigned int pack_f16x2(float x) {
  f16 h = (f16)x;
  f16 l = (f16)(x - (float)h);
  return (unsigned int)__builtin_bit_cast(unsigned short, h)
       | ((unsigned int)__builtin_bit_cast(unsigned short, l) << 16);
}

// read 8 packed u32 from LDS -> hi f16x8, lo f16x8
__device__ __forceinline__ void unpack8(const unsigned int* p, f16x8& hi, f16x8& lo) {
  uint4 w0 = *reinterpret_cast<const uint4*>(p);
  uint4 w1 = *reinterpret_cast<const uint4*>(p + 4);
  union { unsigned int u[4]; f16x8 v; } H, L;
  H.u[0] = (w0.x & 0xffffu) | (w0.y << 16);
  L.u[0] = (w0.x >> 16)     | (w0.y & 0xffff0000u);
  H.u[1] = (w0.z & 0xffffu) | (w0.w << 16);
  L.u[1] = (w0.z >> 16)     | (w0.w & 0xffff0000u);
  H.u[2] = (w1.x & 0xffffu) | (w1.y << 16);
  L.u[2] = (w1.x >> 16)     | (w1.y & 0xffff0000u);
  H.u[3] = (w1.z & 0xffffu) | (w1.w << 16);
  L.u[3] = (w1.z >> 16)     | (w1.w & 0xffff0000u);
  hi = H.v; lo = L.v;
}

// ---------------- Router v2: 4 tokens per wave in registers -----------------
template<int CHUNKS>  // Kin = CHUNKS*256
__global__ __launch_bounds__(256) void router_v2(
    const float* __restrict__ X,
    const float* __restrict__ Wsm,   // [8, Kin]
    const float* __restrict__ Wtk,   // [32, Kin]
    float* __restrict__ iw, int* __restrict__ pidx,
    f16* __restrict__ Xh, f16* __restrict__ Xl)
{
  const int Kin = CHUNKS * 256;
  const int tid = threadIdx.x, wave = tid >> 6, lane = tid & 63;
  __shared__ float sc[4][4][40];
  const size_t t0 = (size_t)blockIdx.x * 16 + wave * 4;

  float4 xv[4][CHUNKS];
  #pragma unroll
  for (int tt = 0; tt < 4; ++tt) {
    const float4* Xp = reinterpret_cast<const float4*>(X + (t0 + tt) * Kin);
    #pragma unroll
    for (int c = 0; c < CHUNKS; ++c) xv[tt][c] = Xp[c * 64 + lane];
  }
  if (Xh) {  // fused split-write
    #pragma unroll
    for (int tt = 0; tt < 4; ++tt)
      #pragma unroll
      for (int c = 0; c < CHUNKS; ++c) {
        f16x4 h, l;
        split4(xv[tt][c], h, l);
        size_t off = (t0 + tt) * Kin + (c * 64 + lane) * 4;
        *reinterpret_cast<f16x4*>(Xh + off) = h;
        *reinterpret_cast<f16x4*>(Xl + off) = l;
      }
  }

  for (int w = 0; w < 40; ++w) {
    const float* Wr = (w < NI) ? (Wsm + (size_t)w * Kin) : (Wtk + (size_t)(w - NI) * Kin);
    const float4* Wp = reinterpret_cast<const float4*>(Wr);
    float p[4] = {};
    #pragma unroll
    for (int c = 0; c < CHUNKS; ++c) {
      float4 wv = Wp[c * 64 + lane];
      #pragma unroll
      for (int tt = 0; tt < 4; ++tt) {
        p[tt] = fmaf(xv[tt][c].x, wv.x, p[tt]);
        p[tt] = fmaf(xv[tt][c].y, wv.y, p[tt]);
        p[tt] = fmaf(xv[tt][c].z, wv.z, p[tt]);
        p[tt] = fmaf(xv[tt][c].w, wv.w, p[tt]);
      }
    }
    #pragma unroll
    for (int tt = 0; tt < 4; ++tt) {
      p[tt] = wave_sum(p[tt]);
      if (lane == 0) sc[wave][tt][w] = p[tt];
    }
  }

  for (int tt = 0; tt < 4; ++tt) {
    float s = (lane < NI) ? sc[wave][tt][lane] : -3.0e38f;
    float m = s;
    #pragma unroll
    for (int off = 4; off; off >>= 1) m = fmaxf(m, __shfl_xor(m, off));
    float e = expf(s - m);
    float sum = e;
    #pragma unroll
    for (int off = 4; off; off >>= 1) sum += __shfl_xor(sum, off);
    if (lane < NI) iw[(t0 + tt) * NI + lane] = e / sum;

    float v = (lane < NP) ? sc[wave][tt][NI + lane] : -3.0e38f;
    int idx = lane;
    #pragma unroll
    for (int j = 0; j < TOPK; ++j) {
      float bv = v; int bi = idx;
      #pragma unroll
      for (int off = 32; off; off >>= 1) {
        float ov = __shfl_xor(bv, off); int oi = __shfl_xor(bi, off);
        if (ov > bv || (ov == bv && oi < bi)) { bv = ov; bi = oi; }
      }
      if (lane == 0) pidx[(t0 + tt) * TOPK + j] = bi;
      if (idx == bi) v = -3.0e38f;
    }
  }
}

// ---------------- Pack B: [K][C] fp32 -> [C][K] fp16 hi/lo (transpose+split)
__global__ __launch_bounds__(256) void pack_bt(
    const float* __restrict__ S, f16* __restrict__ Dh, f16* __restrict__ Dl,
    int C, int K)
{
  __shared__ float T[64][65];
  const int tid = threadIdx.x;
  const int kb = blockIdx.x * 64, cb = blockIdx.y * 64;
  const int tr = tid >> 4, tc = (tid & 15) * 4;
  #pragma unroll
  for (int i = 0; i < 4; ++i) {
    float4 v = *reinterpret_cast<const float4*>(&S[(size_t)(kb + tr + i * 16) * C + cb + tc]);
    T[tr + i * 16][tc + 0] = v.x; T[tr + i * 16][tc + 1] = v.y;
    T[tr + i * 16][tc + 2] = v.z; T[tr + i * 16][tc + 3] = v.w;
  }
  __syncthreads();
  #pragma unroll
  for (int i = 0; i < 4; ++i) {
    int c = tr + i * 16;
    f16x4 vh, vl;
    #pragma unroll
    for (int q = 0; q < 4; ++q) {
      float a = T[tc + q][c];
      f16 h = (f16)a;
      vh[q] = h;
      vl[q] = (f16)(a - (float)h);
    }
    *reinterpret_cast<f16x4*>(&Dh[(size_t)(cb + c) * K + kb + tc]) = vh;
    *reinterpret_cast<f16x4*>(&Dl[(size_t)(cb + c) * K + kb + tc]) = vl;
  }
}

// ---------------- Split-f16 MFMA mixture GEMM (single-buffer) ---------------
// Tile 128 x (32*NFRAG), 4 waves 2x2, wave tile 64 x (16*NFRAG). TBK=32.
// NFRAG=2 -> TBN=64 (grid 3/CU), NFRAG=3 -> 96, NFRAG=4 -> 128.
#define TBM 128
#define TBK 32

template<int NFRAG>
__global__ __launch_bounds__(256, 3) void gemm_split2(
    const f16* __restrict__ Xh, const f16* __restrict__ Xl, int Kin,
    const float* __restrict__ W,                               // [T, 8]
    const f16* __restrict__ Bth, const f16* __restrict__ Btl,  // [N][Ktot]
    float* __restrict__ C, int ldC, int Ktot)
{
  const int TBN = 32 * NFRAG;
  __shared__ f16x8 AhL[512];
  __shared__ f16x8 AlL[512];
  __shared__ f16x8 BhL[TBN * 4];
  __shared__ f16x8 BlL[TBN * 4];
  __shared__ float Ws[TBM][NI];

  const int tid = threadIdx.x;
  const int wave = tid >> 6, lane = tid & 63;
  const int wm = wave >> 1, wn = wave & 1;
  const int fr = lane & 15, ks = lane >> 4;
  const int row0 = blockIdx.x * TBM, c0 = blockIdx.y * TBN;

  for (int i = tid; i < TBM * NI; i += 256)
    Ws[i >> 3][i & 7] = W[(size_t)(row0 + (i >> 3)) * NI + (i & 7)];

  const int s1 = 256 + tid;
  const int ar0 = tid >> 2, kg0 = ((tid & 3) - (ar0 >> 1)) & 3;
  const int ar1 = s1 >> 2,  kg1 = ((s1 & 3) - (ar1 >> 1)) & 3;

  const f16* xh0 = Xh + (size_t)(row0 + ar0) * Kin + kg0 * 8;
  const f16* xh1 = Xh + (size_t)(row0 + ar1) * Kin + kg1 * 8;
  const f16* xl0 = Xl + (size_t)(row0 + ar0) * Kin + kg0 * 8;
  const f16* xl1 = Xl + (size_t)(row0 + ar1) * Kin + kg1 * 8;
  const f16* bh0 = Bth + (size_t)(c0 + ar0) * Ktot + kg0 * 8;
  const f16* bl0 = Btl + (size_t)(c0 + ar0) * Ktot + kg0 * 8;
  // second B issue covers cols [64, TBN) -- only needed for NFRAG>=3
  const int ar1b = (ar1 < TBN) ? ar1 : 0;
  const f16* bh1 = Bth + (size_t)(c0 + ar1b) * Ktot + kg1 * 8;
  const f16* bl1 = Btl + (size_t)(c0 + ar1b) * Ktot + kg1 * 8;
  const bool b2 = (NFRAG == 4) || (NFRAG == 3 && wave < 2);

  f16x8* AhW = &AhL[wave * 64];
  f16x8* AlW = &AlL[wave * 64];
  f16x8* BhW = &BhL[wave * 64];
  f16x8* BlW = &BlL[wave * 64];

  f32x4 acc[4][NFRAG] = {};
  f32x4 cac[4][NFRAG] = {};

  int n = 0, dk0 = 0;
  for (int kt = 0; kt < Ktot; kt += TBK) {
    __syncthreads();
    gload16(xh0 + dk0, AhW);
    gload16(xh1 + dk0, AhW + 256);
    gload16(xl0 + dk0, AlW);
    gload16(xl1 + dk0, AlW + 256);
    gload16(bh0 + kt, BhW);
    gload16(bl0 + kt, BlW);
    if (b2) {
      gload16(bh1 + kt, BhW + 256);
      gload16(bl1 + kt, BlW + 256);
    }
    __syncthreads();

    f16x8 ah[4], al[4], bh[NFRAG], bl[NFRAG];
    #pragma unroll
    for (int mf = 0; mf < 4; ++mf) {
      int ar = wm * 64 + mf * 16 + fr;
      int sl = ar * 4 + (((ar >> 1) + ks) & 3);
      ah[mf] = AhL[sl]; al[mf] = AlL[sl];
    }
    #pragma unroll
    for (int nf = 0; nf < NFRAG; ++nf) {
      int bc = wn * (16 * NFRAG) + nf * 16 + fr;
      int sl = bc * 4 + (((bc >> 1) + ks) & 3);
      bh[nf] = BhL[sl]; bl[nf] = BlL[sl];
    }
    #pragma unroll
    for (int mf = 0; mf < 4; ++mf)
      #pragma unroll
      for (int nf = 0; nf < NFRAG; ++nf) {
        acc[mf][nf] = __builtin_amdgcn_mfma_f32_16x16x32_f16(ah[mf], bh[nf], acc[mf][nf], 0, 0, 0);
        acc[mf][nf] = __builtin_amdgcn_mfma_f32_16x16x32_f16(ah[mf], bl[nf], acc[mf][nf], 0, 0, 0);
        acc[mf][nf] = __builtin_amdgcn_mfma_f32_16x16x32_f16(al[mf], bh[nf], acc[mf][nf], 0, 0, 0);
      }

    dk0 += TBK;
    if (dk0 == Kin) {   // n-pass boundary: fold iw_n into cac, reset acc
      dk0 = 0;
      #pragma unroll
      for (int mf = 0; mf < 4; ++mf) {
        float w0 = Ws[wm * 64 + mf * 16 + ks * 4 + 0][n];
        float w1 = Ws[wm * 64 + mf * 16 + ks * 4 + 1][n];
        float w2 = Ws[wm * 64 + mf * 16 + ks * 4 + 2][n];
        float w3 = Ws[wm * 64 + mf * 16 + ks * 4 + 3][n];
        #pragma unroll
        for (int nf = 0; nf < NFRAG; ++nf) {
          cac[mf][nf][0] = fmaf(w0, acc[mf][nf][0], cac[mf][nf][0]);
          cac[mf][nf][1] = fmaf(w1, acc[mf][nf][1], cac[mf][nf][1]);
          cac[mf][nf][2] = fmaf(w2, acc[mf][nf][2], cac[mf][nf][2]);
          cac[mf][nf][3] = fmaf(w3, acc[mf][nf][3], cac[mf][nf][3]);
          acc[mf][nf] = (f32x4){0.f, 0.f, 0.f, 0.f};
        }
      }
      ++n;
    }
  }

  #pragma unroll
  for (int mf = 0; mf < 4; ++mf)
    #pragma unroll
    for (int nf = 0; nf < NFRAG; ++nf) {
      int col = c0 + wn * (16 * NFRAG) + nf * 16 + fr;
      #pragma unroll
      for (int j = 0; j < 4; ++j) {
        int row = row0 + wm * 64 + mf * 16 + ks * 4 + j;
        C[(size_t)row * ldC + col] = cac[mf][nf][j];
      }
    }
}

// ---------------- Old fp32 mixture GEMM (fallback if ws tiny) ---------------
#define GBM 128
#define GBN 128
#define GBK 16
#define GBMp 132

__global__ __launch_bounds__(256) void gemm_mix(
    const float* __restrict__ X, int Kin,
    const float* __restrict__ W,
    const float* __restrict__ Bm0, const float* __restrict__ Bm1, const float* __restrict__ Bm2,
    int ldB, float* __restrict__ C, int ldC, int Nz)
{
  __shared__ float As[GBK][GBMp];
  __shared__ float Bs[GBK][GBMp];
  __shared__ float Ws[GBM][NI];
  const int tid = threadIdx.x;
  const int row0 = blockIdx.x * GBM;
  const int z = blockIdx.z;
  const float* Bm = (z == 0) ? Bm0 : (z == 1) ? Bm1 : Bm2;
  const int c0 = blockIdx.y * GBN;
  for (int i = tid; i < GBM * NI; i += 256)
    Ws[i >> 3][i & 7] = W[(size_t)(row0 + (i >> 3)) * NI + (i & 7)];
  __syncthreads();

  float acc[8][8] = {};
  const int tr = tid >> 4, tc = tid & 15;
  const int srow = tid >> 2;
  const int sseg = (tid & 3) * 4;
  const int bk = tid >> 4;
  const int bc = (tid & 15) * 4;

  const int Ktot = Kin * NI;
  int n = 0, dk0 = 0;
  for (int kt = 0; kt < Ktot; kt += GBK) {
    __syncthreads();
    #pragma unroll
    for (int p = 0; p < 2; ++p) {
      int r = p * 64 + srow;
      float4 xv = *reinterpret_cast<const float4*>(&X[(size_t)(row0 + r) * Kin + dk0 + sseg]);
      float wgt = Ws[r][n];
      As[sseg + 0][r] = xv.x * wgt;
      As[sseg + 1][r] = xv.y * wgt;
      As[sseg + 2][r] = xv.z * wgt;
      As[sseg + 3][r] = xv.w * wgt;
    }
    #pragma unroll
    for (int p = 0; p < 2; ++p) {
      int cc = p * 64 + bc;
      float4 bv = *reinterpret_cast<const float4*>(&Bm[(size_t)(kt + bk) * ldB + c0 + cc]);
      *reinterpret_cast<float4*>(&Bs[bk][cc]) = bv;
    }
    __syncthreads();
    #pragma unroll
    for (int k = 0; k < GBK; ++k) {
      float4 a0 = *reinterpret_cast<const float4*>(&As[k][tr * 8]);
      float4 a1 = *reinterpret_cast<const float4*>(&As[k][tr * 8 + 4]);
      float4 b0 = *reinterpret_cast<const float4*>(&Bs[k][tc * 8]);
      float4 b1 = *reinterpret_cast<const float4*>(&Bs[k][tc * 8 + 4]);
      float av[8] = {a0.x, a0.y, a0.z, a0.w, a1.x, a1.y, a1.z, a1.w};
      float bv[8] = {b0.x, b0.y, b0.z, b0.w, b1.x, b1.y, b1.z, b1.w};
      #pragma unroll
      for (int i = 0; i < 8; ++i)
        #pragma unroll
        for (int j = 0; j < 8; ++j)
          acc[i][j] = fmaf(av[i], bv[j], acc[i][j]);
    }
    dk0 += GBK;
    if (dk0 == Kin) { dk0 = 0; ++n; }
  }
  #pragma unroll
  for (int i = 0; i < 8; ++i) {
    int row = row0 + tr * 8 + i;
    float* Cp = C + (size_t)row * ldC + z * Nz + c0 + tc * 8;
    float4 o0 = {acc[i][0], acc[i][1], acc[i][2], acc[i][3]};
    float4 o1 = {acc[i][4], acc[i][5], acc[i][6], acc[i][7]};
    *reinterpret_cast<float4*>(Cp) = o0;
    *reinterpret_cast<float4*>(Cp + 4) = o1;
  }
}

// ---------------- Householder chain (3 reflections) -------------------------
// Per circ: if D{circ}h != null, write hi/lo f16 planes [t][256] there
// (skip fp32 writeback); else write fp32 back in place.
__global__ __launch_bounds__(256) void hh_kernel(
    float* __restrict__ X, int ldX,
    const float* __restrict__ P0, const float* __restrict__ P1, const float* __restrict__ P2,
    const int* __restrict__ pidx,
    f16* __restrict__ D0h, f16* __restrict__ D0l,
    f16* __restrict__ D1h, f16* __restrict__ D1l,
    f16* __restrict__ D2h, f16* __restrict__ D2l)
{
  const int tid = threadIdx.x, wave = tid >> 6, lane = tid & 63;
  const int t = blockIdx.x * 4 + wave;
  const int circ = blockIdx.y;
  const float* P = (circ == 0) ? P0 : (circ == 1) ? P1 : P2;
  float* xp = X + (size_t)t * ldX + circ * 256;
  float4 x4 = *reinterpret_cast<float4*>(xp + lane * 4);
  #pragma unroll
  for (int j = 0; j < TOPK; ++j) {
    int id = pidx[t * TOPK + j];
    const float* vp = P + (size_t)id * 256;
    float4 v4 = *reinterpret_cast<const float4*>(vp + lane * 4);
    float ss = v4.x * v4.x + v4.y * v4.y + v4.z * v4.z + v4.w * v4.w;
    ss = wave_sum(ss);
    float inv = 1.0f / sqrtf(ss + 1e-8f);
    float4 vn = {v4.x * inv, v4.y * inv, v4.z * inv, v4.w * inv};
    float dt = vn.x * x4.x + vn.y * x4.y + vn.z * x4.z + vn.w * x4.w;
    dt = wave_sum(dt);
    float d2 = 2.0f * dt;
    x4.x = fmaf(-d2, vn.x, x4.x);
    x4.y = fmaf(-d2, vn.y, x4.y);
    x4.z = fmaf(-d2, vn.z, x4.z);
    x4.w = fmaf(-d2, vn.w, x4.w);
  }
  f16* Dh = (circ == 0) ? D0h : (circ == 1) ? D1h : D2h;
  f16* Dl = (circ == 0) ? D0l : (circ == 1) ? D1l : D2l;
  if (Dh) {
    f16x4 h, l;
    split4(x4, h, l);
    *reinterpret_cast<f16x4*>(Dh + (size_t)t * 256 + lane * 4) = h;
    *reinterpret_cast<f16x4*>(Dl + (size_t)t * 256 + lane * 4) = l;
  } else {
    *reinterpret_cast<float4*>(xp + lane * 4) = x4;
  }
}

// ---------------- MFMA split-f16 flash attention (packed-u32 LDS) + T14 -----
// Reads fp32 qkv directly; splits in-kernel. One (b,h) per block,
// 128 q rows (4 waves x 32). K-tile 64.
__global__ __launch_bounds__(256, 2) void attn_mfma(
    const float* __restrict__ qkv, float* __restrict__ O)
{
  __shared__ f16 Kh[64][40];            // [kj][d]
  __shared__ f16 Kl[64][40];
  __shared__ unsigned int Vtp[32][68];  // [d][kj], packed hi|lo
  __shared__ unsigned int Pp[4][32][68];// per-wave [qi][kj], packed hi|lo

  const int tid = threadIdx.x, wave = tid >> 6, lane = tid & 63;
  const int c = lane & 15, g = lane >> 4;
  const int bh = blockIdx.y, b = bh >> 3, h = bh & 7;
  const int q0 = blockIdx.x * 128;
  const size_t tbase = (size_t)b * 2048;
  const float SCALE = 0.17677669529663687f;  // 1/sqrt(32)

  // Q fragments (scaled, split hi/lo), held in registers
  f16x8 qh[2], ql[2];
  #pragma unroll
  for (int qt = 0; qt < 2; ++qt) {
    const int row = q0 + wave * 32 + qt * 16 + c;
    const float* qp = qkv + (tbase + row) * 768 + h * 32 + g * 8;
    float4 a = *reinterpret_cast<const float4*>(qp);
    float4 b4 = *reinterpret_cast<const float4*>(qp + 4);
    float qv[8] = {a.x, a.y, a.z, a.w, b4.x, b4.y, b4.z, b4.w};
    #pragma unroll
    for (int j = 0; j < 8; ++j) {
      float xs = qv[j] * SCALE;
      f16 hh = (f16)xs;
      qh[qt][j] = hh;
      ql[qt][j] = (f16)(xs - (float)hh);
    }
  }

  const int kj = tid >> 2, dq = (tid & 3) * 8;
  const int vk = tid & 63, vq = (tid >> 6) * 8;

  // T14: prefetch tile 0's K/V fp32 into registers
  float4 rka, rkb, rva, rvb;
  {
    const float* kp = qkv + (tbase + kj) * 768 + 256 + h * 32 + dq;
    rka = *reinterpret_cast<const float4*>(kp);
    rkb = *reinterpret_cast<const float4*>(kp + 4);
    const float* vp = qkv + (tbase + vk) * 768 + 512 + h * 32 + vq;
    rva = *reinterpret_cast<const float4*>(vp);
    rvb = *reinterpret_cast<const float4*>(vp + 4);
  }

  f32x4 sacc[2][4];
  f32x4 oacc[2][2] = {};
  float mrow[2][4] = {{-INFINITY, -INFINITY, -INFINITY, -INFINITY},
                      {-INFINITY, -INFINITY, -INFINITY, -INFINITY}};
  float lrow[2][4] = {};

  for (int k0 = 0; k0 < 2048; k0 += 64) {
    __syncthreads();
    {  // stage from prefetched regs: K split hi/lo, V packed
      float kv[8] = {rka.x, rka.y, rka.z, rka.w, rkb.x, rkb.y, rkb.z, rkb.w};
      f16x8 khi, klo;
      #pragma unroll
      for (int j = 0; j < 8; ++j) {
        f16 hh = (f16)kv[j];
        khi[j] = hh;
        klo[j] = (f16)(kv[j] - (float)hh);
      }
      *reinterpret_cast<f16x8*>(&Kh[kj][dq]) = khi;
      *reinterpret_cast<f16x8*>(&Kl[kj][dq]) = klo;

      float vv[8] = {rva.x, rva.y, rva.z, rva.w, rvb.x, rvb.y, rvb.z, rvb.w};
      #pragma unroll
      for (int j = 0; j < 8; ++j) Vtp[vq + j][vk] = pack_f16x2(vv[j]);
    }
    __syncthreads();
    if (k0 + 64 < 2048) {  // issue next-tile loads; latency hides under compute
      const float* kp = qkv + (tbase + k0 + 64 + kj) * 768 + 256 + h * 32 + dq;
      rka = *reinterpret_cast<const float4*>(kp);
      rkb = *reinterpret_cast<const float4*>(kp + 4);
      const float* vp = qkv + (tbase + k0 + 64 + vk) * 768 + 512 + h * 32 + vq;
      rva = *reinterpret_cast<const float4*>(vp);
      rvb = *reinterpret_cast<const float4*>(vp + 4);
    }

    // QK^T: S[qi = g*4+r + qt*16][kj = c + s*16]
    #pragma unroll
    for (int s = 0; s < 4; ++s) {
      f16x8 kbh = *reinterpret_cast<const f16x8*>(&Kh[s * 16 + c][g * 8]);
      f16x8 kbl = *reinterpret_cast<const f16x8*>(&Kl[s * 16 + c][g * 8]);
      #pragma unroll
      for (int qt = 0; qt < 2; ++qt) {
        f32x4 acc = {0.f, 0.f, 0.f, 0.f};
        acc = __builtin_amdgcn_mfma_f32_16x16x32_f16(qh[qt], kbh, acc, 0, 0, 0);
        acc = __builtin_amdgcn_mfma_f32_16x16x32_f16(qh[qt], kbl, acc, 0, 0, 0);
        acc = __builtin_amdgcn_mfma_f32_16x16x32_f16(ql[qt], kbh, acc, 0, 0, 0);
        sacc[qt][s] = acc;
      }
    }

    // online softmax (rows in 16-lane groups; reduce over c via shfl)
    float alpha[2][4];
    #pragma unroll
    for (int qt = 0; qt < 2; ++qt)
      #pragma unroll
      for (int r = 0; r < 4; ++r) {
        float mt = fmaxf(fmaxf(sacc[qt][0][r], sacc[qt][1][r]),
                         fmaxf(sacc[qt][2][r], sacc[qt][3][r]));
        #pragma unroll
        for (int off = 1; off < 16; off <<= 1) mt = fmaxf(mt, __shfl_xor(mt, off));
        float mn = fmaxf(mrow[qt][r], mt);
        float al = __expf(mrow[qt][r] - mn);
        mrow[qt][r] = mn;
        alpha[qt][r] = al;
        float ps = 0.f;
        #pragma unroll
        for (int s = 0; s < 4; ++s) {
          float p = __expf(sacc[qt][s][r] - mn);
          sacc[qt][s][r] = p;
          ps += p;
        }
        #pragma unroll
        for (int off = 1; off < 16; off <<= 1) ps += __shfl_xor(ps, off);
        lrow[qt][r] = lrow[qt][r] * al + ps;
      }

    // write P (packed hi/lo) to per-wave LDS; no barrier needed (same wave)
    #pragma unroll
    for (int qt = 0; qt < 2; ++qt)
      #pragma unroll
      for (int s = 0; s < 4; ++s)
        #pragma unroll
        for (int r = 0; r < 4; ++r)
          Pp[wave][qt * 16 + g * 4 + r][s * 16 + c] = pack_f16x2(sacc[qt][s][r]);

    // rescale O
    #pragma unroll
    for (int qt = 0; qt < 2; ++qt)
      #pragma unroll
      for (int dh = 0; dh < 2; ++dh)
        #pragma unroll
        for (int r = 0; r < 4; ++r) oacc[qt][dh][r] *= alpha[qt][r];

    // PV: A = P[qi][kj], B = Vt[d][kj]
    #pragma unroll
    for (int ch = 0; ch < 2; ++ch) {
      f16x8 pah[2], pal[2];
      #pragma unroll
      for (int qt = 0; qt < 2; ++qt)
        unpack8(&Pp[wave][qt * 16 + c][ch * 32 + g * 8], pah[qt], pal[qt]);
      #pragma unroll
      for (int dh = 0; dh < 2; ++dh) {
        f16x8 vh, vl;
        unpack8(&Vtp[dh * 16 + c][ch * 32 + g * 8], vh, vl);
        #pragma unroll
        for (int qt = 0; qt < 2; ++qt) {
          oacc[qt][dh] = __builtin_amdgcn_mfma_f32_16x16x32_f16(pah[qt], vh, oacc[qt][dh], 0, 0, 0);
          oacc[qt][dh] = __builtin_amdgcn_mfma_f32_16x16x32_f16(pah[qt], vl, oacc[qt][dh], 0, 0, 0);
          oacc[qt][dh] = __builtin_amdgcn_mfma_f32_16x16x32_f16(pal[qt], vh, oacc[qt][dh], 0, 0, 0);
        }
      }
    }
  }

  // epilogue
  #pragma unroll
  for (int qt = 0; qt < 2; ++qt)
    #pragma unroll
    for (int r = 0; r < 4; ++r) {
      float inv = 1.0f / lrow[qt][r];
      int row = q0 + wave * 32 + qt * 16 + g * 4 + r;
      #pragma unroll
      for (int dh = 0; dh < 2; ++dh)
        O[(tbase + row) * 256 + h * 32 + dh * 16 + c] = oacc[qt][dh][r] * inv;
    }
}

// ---------------- Old fp32 attention (fallback path) ------------------------
__global__ __launch_bounds__(256) void attn_kernel(
    const float* __restrict__ qkv, float* __restrict__ O)
{
  const int tid = threadIdx.x;
  const int wave = tid >> 6, lane = tid & 63;
  const int bh = blockIdx.y, b = bh >> 3, h = bh & 7;
  const int q0 = blockIdx.x * 8;
  const size_t tbase = (size_t)b * 2048;
  const float SCALE = 0.17677669529663687f;

  __shared__ float Ks[64][36];
  __shared__ float Vt[32][68];
  __shared__ float Ps[4][2][64];

  const int wq = __builtin_amdgcn_readfirstlane(wave);
  const float* qr0 = qkv + (tbase + q0 + wq * 2) * 768 + h * 32;
  float qa[32], qb[32];
  #pragma unroll
  for (int i = 0; i < 32; ++i) { qa[i] = qr0[i]; qb[i] = qr0[768 + i]; }

  const int r = lane >> 5, d = lane & 31;
  float m0 = -INFINITY, m1 = -INFINITY, l0 = 0.f, l1 = 0.f, oacc = 0.f;

  for (int k0 = 0; k0 < 2048; k0 += 64) {
    __syncthreads();
    {
      int j = tid >> 2;
      int c = (tid & 3) * 8;
      const float* kp = qkv + (tbase + k0 + j) * 768 + 256 + h * 32 + c;
      float4 ka = *reinterpret_cast<const float4*>(kp);
      float4 kb = *reinterpret_cast<const float4*>(kp + 4);
      *reinterpret_cast<float4*>(&Ks[j][c]) = ka;
      *reinterpret_cast<float4*>(&Ks[j][c + 4]) = kb;
      const float* vp = qkv + (tbase + k0 + j) * 768 + 512 + h * 32 + c;
      float4 va = *reinterpret_cast<const float4*>(vp);
      float4 vb = *reinterpret_cast<const float4*>(vp + 4);
      Vt[c + 0][j] = va.x; Vt[c + 1][j] = va.y; Vt[c + 2][j] = va.z; Vt[c + 3][j] = va.w;
      Vt[c + 4][j] = vb.x; Vt[c + 5][j] = vb.y; Vt[c + 6][j] = vb.z; Vt[c + 7][j] = vb.w;
    }
    __syncthreads();
    float s0 = 0.f, s1 = 0.f;
    #pragma unroll
    for (int dd = 0; dd < 8; ++dd) {
      float4 kv = *reinterpret_cast<const float4*>(&Ks[lane][dd * 4]);
      s0 = fmaf(qa[dd * 4 + 0], kv.x, s0); s1 = fmaf(qb[dd * 4 + 0], kv.x, s1);
      s0 = fmaf(qa[dd * 4 + 1], kv.y, s0); s1 = fmaf(qb[dd * 4 + 1], kv.y, s1);
      s0 = fmaf(qa[dd * 4 + 2], kv.z, s0); s1 = fmaf(qb[dd * 4 + 2], kv.z, s1);
      s0 = fmaf(qa[dd * 4 + 3], kv.w, s0); s1 = fmaf(qb[dd * 4 + 3], kv.w, s1);
    }
    s0 *= SCALE; s1 *= SCALE;
    float mx0 = s0, mx1 = s1;
    #pragma unroll
    for (int off = 32; off; off >>= 1) {
      mx0 = fmaxf(mx0, __shfl_xor(mx0, off));
      mx1 = fmaxf(mx1, __shfl_xor(mx1, off));
    }
    float nm0 = fmaxf(m0, mx0), nm1 = fmaxf(m1, mx1);
    float p0 = expf(s0 - nm0), p1 = expf(s1 - nm1);
    float a0 = expf(m0 - nm0), a1 = expf(m1 - nm1);
    float sp0 = p0, sp1 = p1;
    #pragma unroll
    for (int off = 32; off; off >>= 1) {
      sp0 += __shfl_xor(sp0, off);
      sp1 += __shfl_xor(sp1, off);
    }
    l0 = l0 * a0 + sp0; l1 = l1 * a1 + sp1;
    m0 = nm0; m1 = nm1;
    Ps[wave][0][lane] = p0; Ps[wave][1][lane] = p1;
    oacc *= (r == 0) ? a0 : a1;
    #pragma unroll
    for (int jq = 0; jq < 16; ++jq) {
      float4 pv = *reinterpret_cast<const float4*>(&Ps[wave][r][jq * 4]);
      float4 vv = *reinterpret_cast<const float4*>(&Vt[d][jq * 4]);
      oacc = fmaf(pv.x, vv.x, oacc);
      oacc = fmaf(pv.y, vv.y, oacc);
      oacc = fmaf(pv.z, vv.z, oacc);
      oacc = fmaf(pv.w, vv.w, oacc);
    }
  }
  float lf = (r == 0) ? l0 : l1;
  oacc /= lf;
  O[(tbase + q0 + wave * 2 + r) * 256 + h * 32 + d] = oacc;
}

// ---------------- launch --------------------------------------------------
extern "C" void kernel_launch(void* const* d_in, const int* in_sizes, int n_in,
                              void* d_out, int out_size, void* d_ws, size_t ws_size,
                              hipStream_t stream) {
  const float* x       = (const float*)d_in[0];
  const float* q_in    = (const float*)d_in[1];
  const float* q_proc  = (const float*)d_in[2];
  const float* k_in    = (const float*)d_in[3];
  const float* k_proc  = (const float*)d_in[4];
  const float* v_in    = (const float*)d_in[5];
  const float* v_proc  = (const float*)d_in[6];
  const float* o_proc  = (const float*)d_in[7];
  const float* o_out   = (const float*)d_in[8];
  const float* rd_in   = (const float*)d_in[9];
  const float* rd_proc = (const float*)d_in[10];
  const float* ru_out  = (const float*)d_in[11];
  const float* ru_proc = (const float*)d_in[12];
  float* out = (float*)d_out;
  float* qkv = (float*)d_out;   // [8192,768] fp32 in d_out[0,24MB); dead before final GEMM

  const size_t NEED2 = (768ull << 10) + 768ull * 8192 * 2 * 2 + 8192ull * 1024 * 2 * 2;  // ~59.5MB

  if (ws_size >= NEED2) {
    char* wsb = (char*)d_ws;
    float* iw    = (float*)wsb;                 // 256KB
    float* owt   = (float*)(wsb + (256 << 10)); // 256KB
    int*   pidx  = (int*)(wsb + (512 << 10));   // 128KB
    int*   pidxu = (int*)(wsb + (640 << 10));   // 128KB
    char*  R1    = wsb + (768 << 10);           // packed B for QKV: 25.17MB
    f16* bth_q = (f16*)R1;
    f16* btl_q = (f16*)(R1 + 768ull * 8192 * 2);
    char*  R2    = R1 + 768ull * 8192 * 2 * 2;  // 33.55MB region
    // phase 1 (QKV gemm): Xh/Xl fill all of R2
    f16* Xh = (f16*)R2;
    f16* Xl = (f16*)(R2 + 8192ull * 1024 * 2);
    // R2 reuse after QKV gemm:
    float* obuf  = (float*)R2;                              //  8.39MB
    f16* Oh    = (f16*)(R2 + 8388608);                      //  4.19MB
    f16* Ol    = (f16*)(R2 + 12582912);                     //  4.19MB
    f16* bth_o = (f16*)(R2 + 16777216);                     //  4.19MB
    f16* btl_o = (f16*)(R2 + 20971520);                     //  4.19MB

    // down-router + fused X hi/lo split
    router_v2<4><<<dim3(512), dim3(256), 0, stream>>>(x, rd_in, rd_proc, iw, pidx, Xh, Xl);
    pack_bt<<<dim3(128, 4), dim3(256), 0, stream>>>(q_in, bth_q,                 btl_q,                 256, 8192);
    pack_bt<<<dim3(128, 4), dim3(256), 0, stream>>>(k_in, bth_q + 256ull * 8192, btl_q + 256ull * 8192, 256, 8192);
    pack_bt<<<dim3(128, 4), dim3(256), 0, stream>>>(v_in, bth_q + 512ull * 8192, btl_q + 512ull * 8192, 256, 8192);
    // QKV mixture GEMM: 128x64 tile -> 64x12 = 768 blocks = 3/CU exact
    gemm_split2<2><<<dim3(64, 12), dim3(256), 0, stream>>>(Xh, Xl, 1024, iw, bth_q, btl_q,
                                                           qkv, 768, 8192);
    // Householder (all circuits fp32 in-place)
    hh_kernel<<<dim3(2048, 3), dim3(256), 0, stream>>>(qkv, 768, q_proc, k_proc, v_proc, pidx,
                                                       (f16*)nullptr, (f16*)nullptr,
                                                       (f16*)nullptr, (f16*)nullptr,
                                                       (f16*)nullptr, (f16*)nullptr);
    pack_bt<<<dim3(32, 16), dim3(256), 0, stream>>>(o_out, bth_o, btl_o, 1024, 2048);
    // attention: packed-u32 LDS, qkv-direct, T14 register prefetch
    attn_mfma<<<dim3(16, 32), dim3(256), 0, stream>>>(qkv, obuf);
    // up-router
    router_v2<1><<<dim3(512), dim3(256), 0, stream>>>(obuf, ru_out, ru_proc, owt, pidxu,
                                                      (f16*)nullptr, (f16*)nullptr);
    // Householder-up + fused O hi/lo split
    hh_kernel<<<dim3(2048, 1), dim3(256), 0, stream>>>(obuf, 256, o_proc, o_proc, o_proc, pidxu,
                                                       Oh, Ol,
                                                       (f16*)nullptr, (f16*)nullptr,
                                                       (f16*)nullptr, (f16*)nullptr);
    // output mixture GEMM: 128x64 tile -> 64x16 = 1024 blocks
    gemm_split2<2><<<dim3(64, 16), dim3(256), 0, stream>>>(Oh, Ol, 256, owt, bth_o, btl_o,
                                                           out, 1024, 2048);
  } else {
    // fp32 fallback (fits small ws)
    float* ws = (float*)d_ws;
    float* iw    = ws;
    int*   pidx  = (int*)(ws + 65536);
    float* obuf  = ws + 65536 + 24576;
    float* owt   = obuf + 8192 * 256;
    int*   pidxu = (int*)(owt + 65536);

    router_v2<4><<<dim3(512), dim3(256), 0, stream>>>(x, rd_in, rd_proc, iw, pidx,
                                                      (f16*)nullptr, (f16*)nullptr);
    gemm_mix<<<dim3(64, 2, 3), dim3(256), 0, stream>>>(x, 1024, iw, q_in, k_in, v_in,
                                                       256, qkv, 768, 256);
    hh_kernel<<<dim3(2048, 3), dim3(256), 0, stream>>>(qkv, 768, q_proc, k_proc, v_proc, pidx,
                                                       (f16*)nullptr, (f16*)nullptr,
                                                       (f16*)nullptr, (f16*)nullptr,
                                                       (f16*)nullptr, (f16*)nullptr);
    attn_kernel<<<dim3(256, 32), dim3(256), 0, stream>>>(qkv, obuf);
    router_v2<1><<<dim3(512), dim3(256), 0, stream>>>(obuf, ru_out, ru_proc, owt, pidxu,
                                                      (f16*)nullptr, (f16*)nullptr);
    hh_kernel<<<dim3(2048, 1), dim3(256), 0, stream>>>(obuf, 256, o_proc, o_proc, o_proc, pidxu,
                                                       (f16*)nullptr, (f16*)nullptr,
                                                       (f16*)nullptr, (f16*)nullptr,
                                                       (f16*)nullptr, (f16*)nullptr);
    gemm_mix<<<dim3(64, 8, 1), dim3(256), 0, stream>>>(obuf, 256, owt, o_out, o_out, o_out,
                                                       1024, out, 1024, 1024);
  }
}

// Round 10
// 729.350 us; speedup vs baseline: 1.0214x; 1.0214x over previous
//
#include <hip/hip_runtime.h>
#include <math.h>

// Problem constants
#define NI 8
#define NP 32
#define TOPK 3

typedef _Float16 f16;
typedef f16 f16x8 __attribute__((ext_vector_type(8)));
typedef f16 f16x4 __attribute__((ext_vector_type(4)));
typedef float f32x4 __attribute__((ext_vector_type(4)));

__device__ __forceinline__ float wave_sum(float v) {
  #pragma unroll
  for (int off = 32; off; off >>= 1) v += __shfl_xor(v, off);
  return v;
}

// async 16B global -> LDS (dest = wave-uniform base + lane*16)
__device__ __forceinline__ void gload16(const void* g, void* l) {
  __builtin_amdgcn_global_load_lds(
      (const __attribute__((address_space(1))) unsigned int*)g,
      (__attribute__((address_space(3))) unsigned int*)l, 16, 0, 0);
}

__device__ __forceinline__ void split4(float4 v, f16x4& h, f16x4& l) {
  h[0] = (f16)v.x; l[0] = (f16)(v.x - (float)h[0]);
  h[1] = (f16)v.y; l[1] = (f16)(v.y - (float)h[1]);
  h[2] = (f16)v.z; l[2] = (f16)(v.z - (float)h[2]);
  h[3] = (f16)v.w; l[3] = (f16)(v.w - (float)h[3]);
}

// pack one fp32 into (hi f16 | lo f16 << 16)
__device__ __forceinline__ unsigned int pack_f16x2(float x) {
  f16 h = (f16)x;
  f16 l = (f16)(x - (float)h);
  return (unsigned int)__builtin_bit_cast(unsigned short, h)
       | ((unsigned int)__builtin_bit_cast(unsigned short, l) << 16);
}

// read 8 packed u32 from LDS -> hi f16x8, lo f16x8
__device__ __forceinline__ void unpack8(const unsigned int* p, f16x8& hi, f16x8& lo) {
  uint4 w0 = *reinterpret_cast<const uint4*>(p);
  uint4 w1 = *reinterpret_cast<const uint4*>(p + 4);
  union { unsigned int u[4]; f16x8 v; } H, L;
  H.u[0] = (w0.x & 0xffffu) | (w0.y << 16);
  L.u[0] = (w0.x >> 16)     | (w0.y & 0xffff0000u);
  H.u[1] = (w0.z & 0xffffu) | (w0.w << 16);
  L.u[1] = (w0.z >> 16)     | (w0.w & 0xffff0000u);
  H.u[2] = (w1.x & 0xffffu) | (w1.y << 16);
  L.u[2] = (w1.x >> 16)     | (w1.y & 0xffff0000u);
  H.u[3] = (w1.z & 0xffffu) | (w1.w << 16);
  L.u[3] = (w1.z >> 16)     | (w1.w & 0xffff0000u);
  hi = H.v; lo = L.v;
}

// ---------------- Router v2: 4 tokens per wave in registers -----------------
template<int CHUNKS>  // Kin = CHUNKS*256
__global__ __launch_bounds__(256) void router_v2(
    const float* __restrict__ X,
    const float* __restrict__ Wsm,   // [8, Kin]
    const float* __restrict__ Wtk,   // [32, Kin]
    float* __restrict__ iw, int* __restrict__ pidx,
    f16* __restrict__ Xh, f16* __restrict__ Xl)
{
  const int Kin = CHUNKS * 256;
  const int tid = threadIdx.x, wave = tid >> 6, lane = tid & 63;
  __shared__ float sc[4][4][40];
  const size_t t0 = (size_t)blockIdx.x * 16 + wave * 4;

  float4 xv[4][CHUNKS];
  #pragma unroll
  for (int tt = 0; tt < 4; ++tt) {
    const float4* Xp = reinterpret_cast<const float4*>(X + (t0 + tt) * Kin);
    #pragma unroll
    for (int c = 0; c < CHUNKS; ++c) xv[tt][c] = Xp[c * 64 + lane];
  }
  if (Xh) {  // fused split-write
    #pragma unroll
    for (int tt = 0; tt < 4; ++tt)
      #pragma unroll
      for (int c = 0; c < CHUNKS; ++c) {
        f16x4 h, l;
        split4(xv[tt][c], h, l);
        size_t off = (t0 + tt) * Kin + (c * 64 + lane) * 4;
        *reinterpret_cast<f16x4*>(Xh + off) = h;
        *reinterpret_cast<f16x4*>(Xl + off) = l;
      }
  }

  for (int w = 0; w < 40; ++w) {
    const float* Wr = (w < NI) ? (Wsm + (size_t)w * Kin) : (Wtk + (size_t)(w - NI) * Kin);
    const float4* Wp = reinterpret_cast<const float4*>(Wr);
    float p[4] = {};
    #pragma unroll
    for (int c = 0; c < CHUNKS; ++c) {
      float4 wv = Wp[c * 64 + lane];
      #pragma unroll
      for (int tt = 0; tt < 4; ++tt) {
        p[tt] = fmaf(xv[tt][c].x, wv.x, p[tt]);
        p[tt] = fmaf(xv[tt][c].y, wv.y, p[tt]);
        p[tt] = fmaf(xv[tt][c].z, wv.z, p[tt]);
        p[tt] = fmaf(xv[tt][c].w, wv.w, p[tt]);
      }
    }
    #pragma unroll
    for (int tt = 0; tt < 4; ++tt) {
      p[tt] = wave_sum(p[tt]);
      if (lane == 0) sc[wave][tt][w] = p[tt];
    }
  }

  for (int tt = 0; tt < 4; ++tt) {
    float s = (lane < NI) ? sc[wave][tt][lane] : -3.0e38f;
    float m = s;
    #pragma unroll
    for (int off = 4; off; off >>= 1) m = fmaxf(m, __shfl_xor(m, off));
    float e = expf(s - m);
    float sum = e;
    #pragma unroll
    for (int off = 4; off; off >>= 1) sum += __shfl_xor(sum, off);
    if (lane < NI) iw[(t0 + tt) * NI + lane] = e / sum;

    float v = (lane < NP) ? sc[wave][tt][NI + lane] : -3.0e38f;
    int idx = lane;
    #pragma unroll
    for (int j = 0; j < TOPK; ++j) {
      float bv = v; int bi = idx;
      #pragma unroll
      for (int off = 32; off; off >>= 1) {
        float ov = __shfl_xor(bv, off); int oi = __shfl_xor(bi, off);
        if (ov > bv || (ov == bv && oi < bi)) { bv = ov; bi = oi; }
      }
      if (lane == 0) pidx[(t0 + tt) * TOPK + j] = bi;
      if (idx == bi) v = -3.0e38f;
    }
  }
}

// ---------------- Fused up-router + Householder-up + O hi/lo split ----------
// obuf [8192][256]; per wave 4 tokens; lane holds float4 (= hh layout).
__global__ __launch_bounds__(256) void router_hh_up(
    const float* __restrict__ O,
    const float* __restrict__ Wsm,   // ru_out  [8, 256]
    const float* __restrict__ Wtk,   // ru_proc [32, 256]
    const float* __restrict__ Pm,    // o_proc  [32, 256]
    float* __restrict__ owt, int* __restrict__ pidxu,
    f16* __restrict__ Oh, f16* __restrict__ Ol)
{
  const int tid = threadIdx.x, wave = tid >> 6, lane = tid & 63;
  __shared__ float sc[4][4][40];
  const size_t t0 = (size_t)blockIdx.x * 16 + wave * 4;

  float4 xv[4];
  #pragma unroll
  for (int tt = 0; tt < 4; ++tt)
    xv[tt] = *reinterpret_cast<const float4*>(O + (t0 + tt) * 256 + lane * 4);

  for (int w = 0; w < 40; ++w) {
    const float* Wr = (w < NI) ? (Wsm + (size_t)w * 256) : (Wtk + (size_t)(w - NI) * 256);
    float4 wv = *reinterpret_cast<const float4*>(Wr + lane * 4);
    float p[4];
    #pragma unroll
    for (int tt = 0; tt < 4; ++tt) {
      float q = 0.f;
      q = fmaf(xv[tt].x, wv.x, q); q = fmaf(xv[tt].y, wv.y, q);
      q = fmaf(xv[tt].z, wv.z, q); q = fmaf(xv[tt].w, wv.w, q);
      p[tt] = wave_sum(q);
    }
    #pragma unroll
    for (int tt = 0; tt < 4; ++tt)
      if (lane == 0) sc[wave][tt][w] = p[tt];
  }

  for (int tt = 0; tt < 4; ++tt) {
    // softmax over first 8
    float s = (lane < NI) ? sc[wave][tt][lane] : -3.0e38f;
    float m = s;
    #pragma unroll
    for (int off = 4; off; off >>= 1) m = fmaxf(m, __shfl_xor(m, off));
    float e = expf(s - m);
    float sum = e;
    #pragma unroll
    for (int off = 4; off; off >>= 1) sum += __shfl_xor(sum, off);
    if (lane < NI) owt[(t0 + tt) * NI + lane] = e / sum;

    // top-3 of 32 (wave-uniform results after butterfly)
    float v = (lane < NP) ? sc[wave][tt][NI + lane] : -3.0e38f;
    int idx = lane;
    int pid[TOPK];
    #pragma unroll
    for (int j = 0; j < TOPK; ++j) {
      float bv = v; int bi = idx;
      #pragma unroll
      for (int off = 32; off; off >>= 1) {
        float ov = __shfl_xor(bv, off); int oi = __shfl_xor(bi, off);
        if (ov > bv || (ov == bv && oi < bi)) { bv = ov; bi = oi; }
      }
      pid[j] = bi;
      if (lane == 0) pidxu[(t0 + tt) * TOPK + j] = bi;
      if (idx == bi) v = -3.0e38f;
    }

    // Householder chain (3 reflections) in-register
    float4 x4 = xv[tt];
    #pragma unroll
    for (int j = 0; j < TOPK; ++j) {
      const float* vp = Pm + (size_t)pid[j] * 256;
      float4 v4 = *reinterpret_cast<const float4*>(vp + lane * 4);
      float ss = v4.x * v4.x + v4.y * v4.y + v4.z * v4.z + v4.w * v4.w;
      ss = wave_sum(ss);
      float inv = 1.0f / sqrtf(ss + 1e-8f);
      float4 vn = {v4.x * inv, v4.y * inv, v4.z * inv, v4.w * inv};
      float dt = vn.x * x4.x + vn.y * x4.y + vn.z * x4.z + vn.w * x4.w;
      dt = wave_sum(dt);
      float d2 = 2.0f * dt;
      x4.x = fmaf(-d2, vn.x, x4.x);
      x4.y = fmaf(-d2, vn.y, x4.y);
      x4.z = fmaf(-d2, vn.z, x4.z);
      x4.w = fmaf(-d2, vn.w, x4.w);
    }
    f16x4 h, l;
    split4(x4, h, l);
    *reinterpret_cast<f16x4*>(Oh + (t0 + tt) * 256 + lane * 4) = h;
    *reinterpret_cast<f16x4*>(Ol + (t0 + tt) * 256 + lane * 4) = l;
  }
}

// ---------------- Pack B: [K][C] fp32 -> [C][K] fp16 hi/lo (transpose+split)
__global__ __launch_bounds__(256) void pack_bt(
    const float* __restrict__ S, f16* __restrict__ Dh, f16* __restrict__ Dl,
    int C, int K)
{
  __shared__ float T[64][65];
  const int tid = threadIdx.x;
  const int kb = blockIdx.x * 64, cb = blockIdx.y * 64;
  const int tr = tid >> 4, tc = (tid & 15) * 4;
  #pragma unroll
  for (int i = 0; i < 4; ++i) {
    float4 v = *reinterpret_cast<const float4*>(&S[(size_t)(kb + tr + i * 16) * C + cb + tc]);
    T[tr + i * 16][tc + 0] = v.x; T[tr + i * 16][tc + 1] = v.y;
    T[tr + i * 16][tc + 2] = v.z; T[tr + i * 16][tc + 3] = v.w;
  }
  __syncthreads();
  #pragma unroll
  for (int i = 0; i < 4; ++i) {
    int c = tr + i * 16;
    f16x4 vh, vl;
    #pragma unroll
    for (int q = 0; q < 4; ++q) {
      float a = T[tc + q][c];
      f16 h = (f16)a;
      vh[q] = h;
      vl[q] = (f16)(a - (float)h);
    }
    *reinterpret_cast<f16x4*>(&Dh[(size_t)(cb + c) * K + kb + tc]) = vh;
    *reinterpret_cast<f16x4*>(&Dl[(size_t)(cb + c) * K + kb + tc]) = vl;
  }
}

// ---------------- Split-f16 MFMA mixture GEMM (single-buffer) ---------------
// Tile 128 x (32*NFRAG), 4 waves 2x2, wave tile 64 x (16*NFRAG). TBK=32.
#define TBM 128
#define TBK 32

template<int NFRAG>   // 3 -> TBN=96 (QKV), 4 -> TBN=128 (out-proj)
__global__ __launch_bounds__(256, 3) void gemm_split2(
    const f16* __restrict__ Xh, const f16* __restrict__ Xl, int Kin,
    const float* __restrict__ W,                               // [T, 8]
    const f16* __restrict__ Bth, const f16* __restrict__ Btl,  // [N][Ktot]
    float* __restrict__ C, int ldC, int Ktot)
{
  const int TBN = 32 * NFRAG;
  __shared__ f16x8 AhL[512];
  __shared__ f16x8 AlL[512];
  __shared__ f16x8 BhL[TBN * 4];
  __shared__ f16x8 BlL[TBN * 4];
  __shared__ float Ws[TBM][NI];

  const int tid = threadIdx.x;
  const int wave = tid >> 6, lane = tid & 63;
  const int wm = wave >> 1, wn = wave & 1;
  const int fr = lane & 15, ks = lane >> 4;
  const int row0 = blockIdx.x * TBM, c0 = blockIdx.y * TBN;

  for (int i = tid; i < TBM * NI; i += 256)
    Ws[i >> 3][i & 7] = W[(size_t)(row0 + (i >> 3)) * NI + (i & 7)];

  const int s1 = 256 + tid;
  const int ar0 = tid >> 2, kg0 = ((tid & 3) - (ar0 >> 1)) & 3;
  const int ar1 = s1 >> 2,  kg1 = ((s1 & 3) - (ar1 >> 1)) & 3;

  const f16* xh0 = Xh + (size_t)(row0 + ar0) * Kin + kg0 * 8;
  const f16* xh1 = Xh + (size_t)(row0 + ar1) * Kin + kg1 * 8;
  const f16* xl0 = Xl + (size_t)(row0 + ar0) * Kin + kg0 * 8;
  const f16* xl1 = Xl + (size_t)(row0 + ar1) * Kin + kg1 * 8;
  const f16* bh0 = Bth + (size_t)(c0 + ar0) * Ktot + kg0 * 8;
  const f16* bl0 = Btl + (size_t)(c0 + ar0) * Ktot + kg0 * 8;
  const int ar1b = (ar1 < TBN) ? ar1 : 0;
  const f16* bh1 = Bth + (size_t)(c0 + ar1b) * Ktot + kg1 * 8;
  const f16* bl1 = Btl + (size_t)(c0 + ar1b) * Ktot + kg1 * 8;
  const bool b2 = (NFRAG == 4) || (NFRAG == 3 && wave < 2);

  f16x8* AhW = &AhL[wave * 64];
  f16x8* AlW = &AlL[wave * 64];
  f16x8* BhW = &BhL[wave * 64];
  f16x8* BlW = &BlL[wave * 64];

  f32x4 acc[4][NFRAG] = {};
  f32x4 cac[4][NFRAG] = {};

  int n = 0, dk0 = 0;
  for (int kt = 0; kt < Ktot; kt += TBK) {
    __syncthreads();
    gload16(xh0 + dk0, AhW);
    gload16(xh1 + dk0, AhW + 256);
    gload16(xl0 + dk0, AlW);
    gload16(xl1 + dk0, AlW + 256);
    gload16(bh0 + kt, BhW);
    gload16(bl0 + kt, BlW);
    if (b2) {
      gload16(bh1 + kt, BhW + 256);
      gload16(bl1 + kt, BlW + 256);
    }
    __syncthreads();

    f16x8 ah[4], al[4], bh[NFRAG], bl[NFRAG];
    #pragma unroll
    for (int mf = 0; mf < 4; ++mf) {
      int ar = wm * 64 + mf * 16 + fr;
      int sl = ar * 4 + (((ar >> 1) + ks) & 3);
      ah[mf] = AhL[sl]; al[mf] = AlL[sl];
    }
    #pragma unroll
    for (int nf = 0; nf < NFRAG; ++nf) {
      int bc = wn * (16 * NFRAG) + nf * 16 + fr;
      int sl = bc * 4 + (((bc >> 1) + ks) & 3);
      bh[nf] = BhL[sl]; bl[nf] = BlL[sl];
    }
    #pragma unroll
    for (int mf = 0; mf < 4; ++mf)
      #pragma unroll
      for (int nf = 0; nf < NFRAG; ++nf) {
        acc[mf][nf] = __builtin_amdgcn_mfma_f32_16x16x32_f16(ah[mf], bh[nf], acc[mf][nf], 0, 0, 0);
        acc[mf][nf] = __builtin_amdgcn_mfma_f32_16x16x32_f16(ah[mf], bl[nf], acc[mf][nf], 0, 0, 0);
        acc[mf][nf] = __builtin_amdgcn_mfma_f32_16x16x32_f16(al[mf], bh[nf], acc[mf][nf], 0, 0, 0);
      }

    dk0 += TBK;
    if (dk0 == Kin) {   // n-pass boundary: fold iw_n into cac, reset acc
      dk0 = 0;
      #pragma unroll
      for (int mf = 0; mf < 4; ++mf) {
        float w0 = Ws[wm * 64 + mf * 16 + ks * 4 + 0][n];
        float w1 = Ws[wm * 64 + mf * 16 + ks * 4 + 1][n];
        float w2 = Ws[wm * 64 + mf * 16 + ks * 4 + 2][n];
        float w3 = Ws[wm * 64 + mf * 16 + ks * 4 + 3][n];
        #pragma unroll
        for (int nf = 0; nf < NFRAG; ++nf) {
          cac[mf][nf][0] = fmaf(w0, acc[mf][nf][0], cac[mf][nf][0]);
          cac[mf][nf][1] = fmaf(w1, acc[mf][nf][1], cac[mf][nf][1]);
          cac[mf][nf][2] = fmaf(w2, acc[mf][nf][2], cac[mf][nf][2]);
          cac[mf][nf][3] = fmaf(w3, acc[mf][nf][3], cac[mf][nf][3]);
          acc[mf][nf] = (f32x4){0.f, 0.f, 0.f, 0.f};
        }
      }
      ++n;
    }
  }

  #pragma unroll
  for (int mf = 0; mf < 4; ++mf)
    #pragma unroll
    for (int nf = 0; nf < NFRAG; ++nf) {
      int col = c0 + wn * (16 * NFRAG) + nf * 16 + fr;
      #pragma unroll
      for (int j = 0; j < 4; ++j) {
        int row = row0 + wm * 64 + mf * 16 + ks * 4 + j;
        C[(size_t)row * ldC + col] = cac[mf][nf][j];
      }
    }
}

// ---------------- Old fp32 mixture GEMM (fallback if ws tiny) ---------------
#define GBM 128
#define GBN 128
#define GBK 16
#define GBMp 132

__global__ __launch_bounds__(256) void gemm_mix(
    const float* __restrict__ X, int Kin,
    const float* __restrict__ W,
    const float* __restrict__ Bm0, const float* __restrict__ Bm1, const float* __restrict__ Bm2,
    int ldB, float* __restrict__ C, int ldC, int Nz)
{
  __shared__ float As[GBK][GBMp];
  __shared__ float Bs[GBK][GBMp];
  __shared__ float Ws[GBM][NI];
  const int tid = threadIdx.x;
  const int row0 = blockIdx.x * GBM;
  const int z = blockIdx.z;
  const float* Bm = (z == 0) ? Bm0 : (z == 1) ? Bm1 : Bm2;
  const int c0 = blockIdx.y * GBN;
  for (int i = tid; i < GBM * NI; i += 256)
    Ws[i >> 3][i & 7] = W[(size_t)(row0 + (i >> 3)) * NI + (i & 7)];
  __syncthreads();

  float acc[8][8] = {};
  const int tr = tid >> 4, tc = tid & 15;
  const int srow = tid >> 2;
  const int sseg = (tid & 3) * 4;
  const int bk = tid >> 4;
  const int bc = (tid & 15) * 4;

  const int Ktot = Kin * NI;
  int n = 0, dk0 = 0;
  for (int kt = 0; kt < Ktot; kt += GBK) {
    __syncthreads();
    #pragma unroll
    for (int p = 0; p < 2; ++p) {
      int r = p * 64 + srow;
      float4 xv = *reinterpret_cast<const float4*>(&X[(size_t)(row0 + r) * Kin + dk0 + sseg]);
      float wgt = Ws[r][n];
      As[sseg + 0][r] = xv.x * wgt;
      As[sseg + 1][r] = xv.y * wgt;
      As[sseg + 2][r] = xv.z * wgt;
      As[sseg + 3][r] = xv.w * wgt;
    }
    #pragma unroll
    for (int p = 0; p < 2; ++p) {
      int cc = p * 64 + bc;
      float4 bv = *reinterpret_cast<const float4*>(&Bm[(size_t)(kt + bk) * ldB + c0 + cc]);
      *reinterpret_cast<float4*>(&Bs[bk][cc]) = bv;
    }
    __syncthreads();
    #pragma unroll
    for (int k = 0; k < GBK; ++k) {
      float4 a0 = *reinterpret_cast<const float4*>(&As[k][tr * 8]);
      float4 a1 = *reinterpret_cast<const float4*>(&As[k][tr * 8 + 4]);
      float4 b0 = *reinterpret_cast<const float4*>(&Bs[k][tc * 8]);
      float4 b1 = *reinterpret_cast<const float4*>(&Bs[k][tc * 8 + 4]);
      float av[8] = {a0.x, a0.y, a0.z, a0.w, a1.x, a1.y, a1.z, a1.w};
      float bv[8] = {b0.x, b0.y, b0.z, b0.w, b1.x, b1.y, b1.z, b1.w};
      #pragma unroll
      for (int i = 0; i < 8; ++i)
        #pragma unroll
        for (int j = 0; j < 8; ++j)
          acc[i][j] = fmaf(av[i], bv[j], acc[i][j]);
    }
    dk0 += GBK;
    if (dk0 == Kin) { dk0 = 0; ++n; }
  }
  #pragma unroll
  for (int i = 0; i < 8; ++i) {
    int row = row0 + tr * 8 + i;
    float* Cp = C + (size_t)row * ldC + z * Nz + c0 + tc * 8;
    float4 o0 = {acc[i][0], acc[i][1], acc[i][2], acc[i][3]};
    float4 o1 = {acc[i][4], acc[i][5], acc[i][6], acc[i][7]};
    *reinterpret_cast<float4*>(Cp) = o0;
    *reinterpret_cast<float4*>(Cp + 4) = o1;
  }
}

// ---------------- Householder chain (3 reflections) -------------------------
// circ==2 && Vpk: write packed (hi|lo) u32 plane [t][256] (skip fp32 writeback).
__global__ __launch_bounds__(256) void hh_kernel(
    float* __restrict__ X, int ldX,
    const float* __restrict__ P0, const float* __restrict__ P1, const float* __restrict__ P2,
    const int* __restrict__ pidx,
    unsigned int* __restrict__ Vpk)
{
  const int tid = threadIdx.x, wave = tid >> 6, lane = tid & 63;
  const int t = blockIdx.x * 4 + wave;
  const int circ = blockIdx.y;
  const float* P = (circ == 0) ? P0 : (circ == 1) ? P1 : P2;
  float* xp = X + (size_t)t * ldX + circ * 256;
  float4 x4 = *reinterpret_cast<float4*>(xp + lane * 4);
  #pragma unroll
  for (int j = 0; j < TOPK; ++j) {
    int id = pidx[t * TOPK + j];
    const float* vp = P + (size_t)id * 256;
    float4 v4 = *reinterpret_cast<const float4*>(vp + lane * 4);
    float ss = v4.x * v4.x + v4.y * v4.y + v4.z * v4.z + v4.w * v4.w;
    ss = wave_sum(ss);
    float inv = 1.0f / sqrtf(ss + 1e-8f);
    float4 vn = {v4.x * inv, v4.y * inv, v4.z * inv, v4.w * inv};
    float dt = vn.x * x4.x + vn.y * x4.y + vn.z * x4.z + vn.w * x4.w;
    dt = wave_sum(dt);
    float d2 = 2.0f * dt;
    x4.x = fmaf(-d2, vn.x, x4.x);
    x4.y = fmaf(-d2, vn.y, x4.y);
    x4.z = fmaf(-d2, vn.z, x4.z);
    x4.w = fmaf(-d2, vn.w, x4.w);
  }
  if (circ == 2 && Vpk) {
    uint4 pk = {pack_f16x2(x4.x), pack_f16x2(x4.y), pack_f16x2(x4.z), pack_f16x2(x4.w)};
    *reinterpret_cast<uint4*>(Vpk + (size_t)t * 256 + lane * 4) = pk;
  } else {
    *reinterpret_cast<float4*>(xp + lane * 4) = x4;
  }
}

// ---------------- MFMA split-f16 flash attention (packed-u32 LDS) + T14 -----
// Q,K fp32 from qkv (split in-kernel); V pre-packed u32 plane. One (b,h) per
// block, 128 q rows (4 waves x 32). K-tile 64.
__global__ __launch_bounds__(256, 2) void attn_mfma(
    const float* __restrict__ qkv, const unsigned int* __restrict__ Vpk,
    float* __restrict__ O)
{
  __shared__ f16 Kh[64][40];            // [kj][d]
  __shared__ f16 Kl[64][40];
  __shared__ unsigned int Vtp[32][68];  // [d][kj], packed hi|lo
  __shared__ unsigned int Pp[4][32][68];// per-wave [qi][kj], packed hi|lo

  const int tid = threadIdx.x, wave = tid >> 6, lane = tid & 63;
  const int c = lane & 15, g = lane >> 4;
  const int bh = blockIdx.y, b = bh >> 3, h = bh & 7;
  const int q0 = blockIdx.x * 128;
  const size_t tbase = (size_t)b * 2048;
  const float SCALE = 0.17677669529663687f;  // 1/sqrt(32)

  // Q fragments (scaled, split hi/lo), held in registers
  f16x8 qh[2], ql[2];
  #pragma unroll
  for (int qt = 0; qt < 2; ++qt) {
    const int row = q0 + wave * 32 + qt * 16 + c;
    const float* qp = qkv + (tbase + row) * 768 + h * 32 + g * 8;
    float4 a = *reinterpret_cast<const float4*>(qp);
    float4 b4 = *reinterpret_cast<const float4*>(qp + 4);
    float qv[8] = {a.x, a.y, a.z, a.w, b4.x, b4.y, b4.z, b4.w};
    #pragma unroll
    for (int j = 0; j < 8; ++j) {
      float xs = qv[j] * SCALE;
      f16 hh = (f16)xs;
      qh[qt][j] = hh;
      ql[qt][j] = (f16)(xs - (float)hh);
    }
  }

  const int kj = tid >> 2, dq = (tid & 3) * 8;
  const int vk = tid & 63, vq = (tid >> 6) * 8;

  // T14: prefetch tile 0's K fp32 and V packed into registers
  float4 rka, rkb;
  uint4 rv0, rv1;
  {
    const float* kp = qkv + (tbase + kj) * 768 + 256 + h * 32 + dq;
    rka = *reinterpret_cast<const float4*>(kp);
    rkb = *reinterpret_cast<const float4*>(kp + 4);
    const unsigned int* vp = Vpk + (tbase + vk) * 256 + h * 32 + vq;
    rv0 = *reinterpret_cast<const uint4*>(vp);
    rv1 = *reinterpret_cast<const uint4*>(vp + 4);
  }

  f32x4 sacc[2][4];
  f32x4 oacc[2][2] = {};
  float mrow[2][4] = {{-INFINITY, -INFINITY, -INFINITY, -INFINITY},
                      {-INFINITY, -INFINITY, -INFINITY, -INFINITY}};
  float lrow[2][4] = {};

  for (int k0 = 0; k0 < 2048; k0 += 64) {
    __syncthreads();
    {  // stage from prefetched regs: K split hi/lo, V straight u32 copies
      float kv[8] = {rka.x, rka.y, rka.z, rka.w, rkb.x, rkb.y, rkb.z, rkb.w};
      f16x8 khi, klo;
      #pragma unroll
      for (int j = 0; j < 8; ++j) {
        f16 hh = (f16)kv[j];
        khi[j] = hh;
        klo[j] = (f16)(kv[j] - (float)hh);
      }
      *reinterpret_cast<f16x8*>(&Kh[kj][dq]) = khi;
      *reinterpret_cast<f16x8*>(&Kl[kj][dq]) = klo;

      Vtp[vq + 0][vk] = rv0.x; Vtp[vq + 1][vk] = rv0.y;
      Vtp[vq + 2][vk] = rv0.z; Vtp[vq + 3][vk] = rv0.w;
      Vtp[vq + 4][vk] = rv1.x; Vtp[vq + 5][vk] = rv1.y;
      Vtp[vq + 6][vk] = rv1.z; Vtp[vq + 7][vk] = rv1.w;
    }
    __syncthreads();
    if (k0 + 64 < 2048) {  // issue next-tile loads; latency hides under compute
      const float* kp = qkv + (tbase + k0 + 64 + kj) * 768 + 256 + h * 32 + dq;
      rka = *reinterpret_cast<const float4*>(kp);
      rkb = *reinterpret_cast<const float4*>(kp + 4);
      const unsigned int* vp = Vpk + (tbase + k0 + 64 + vk) * 256 + h * 32 + vq;
      rv0 = *reinterpret_cast<const uint4*>(vp);
      rv1 = *reinterpret_cast<const uint4*>(vp + 4);
    }

    // QK^T: S[qi = g*4+r + qt*16][kj = c + s*16]
    #pragma unroll
    for (int s = 0; s < 4; ++s) {
      f16x8 kbh = *reinterpret_cast<const f16x8*>(&Kh[s * 16 + c][g * 8]);
      f16x8 kbl = *reinterpret_cast<const f16x8*>(&Kl[s * 16 + c][g * 8]);
      #pragma unroll
      for (int qt = 0; qt < 2; ++qt) {
        f32x4 acc = {0.f, 0.f, 0.f, 0.f};
        acc = __builtin_amdgcn_mfma_f32_16x16x32_f16(qh[qt], kbh, acc, 0, 0, 0);
        acc = __builtin_amdgcn_mfma_f32_16x16x32_f16(qh[qt], kbl, acc, 0, 0, 0);
        acc = __builtin_amdgcn_mfma_f32_16x16x32_f16(ql[qt], kbh, acc, 0, 0, 0);
        sacc[qt][s] = acc;
      }
    }

    // online softmax (rows in 16-lane groups; reduce over c via shfl)
    float alpha[2][4];
    #pragma unroll
    for (int qt = 0; qt < 2; ++qt)
      #pragma unroll
      for (int r = 0; r < 4; ++r) {
        float mt = fmaxf(fmaxf(sacc[qt][0][r], sacc[qt][1][r]),
                         fmaxf(sacc[qt][2][r], sacc[qt][3][r]));
        #pragma unroll
        for (int off = 1; off < 16; off <<= 1) mt = fmaxf(mt, __shfl_xor(mt, off));
        float mn = fmaxf(mrow[qt][r], mt);
        float al = __expf(mrow[qt][r] - mn);
        mrow[qt][r] = mn;
        alpha[qt][r] = al;
        float ps = 0.f;
        #pragma unroll
        for (int s = 0; s < 4; ++s) {
          float p = __expf(sacc[qt][s][r] - mn);
          sacc[qt][s][r] = p;
          ps += p;
        }
        #pragma unroll
        for (int off = 1; off < 16; off <<= 1) ps += __shfl_xor(ps, off);
        lrow[qt][r] = lrow[qt][r] * al + ps;
      }

    // write P (packed hi/lo) to per-wave LDS; no barrier needed (same wave)
    #pragma unroll
    for (int qt = 0; qt < 2; ++qt)
      #pragma unroll
      for (int s = 0; s < 4; ++s)
        #pragma unroll
        for (int r = 0; r < 4; ++r)
          Pp[wave][qt * 16 + g * 4 + r][s * 16 + c] = pack_f16x2(sacc[qt][s][r]);

    // rescale O
    #pragma unroll
    for (int qt = 0; qt < 2; ++qt)
      #pragma unroll
      for (int dh = 0; dh < 2; ++dh)
        #pragma unroll
        for (int r = 0; r < 4; ++r) oacc[qt][dh][r] *= alpha[qt][r];

    // PV: A = P[qi][kj], B = Vt[d][kj]
    #pragma unroll
    for (int ch = 0; ch < 2; ++ch) {
      f16x8 pah[2], pal[2];
      #pragma unroll
      for (int qt = 0; qt < 2; ++qt)
        unpack8(&Pp[wave][qt * 16 + c][ch * 32 + g * 8], pah[qt], pal[qt]);
      #pragma unroll
      for (int dh = 0; dh < 2; ++dh) {
        f16x8 vh, vl;
        unpack8(&Vtp[dh * 16 + c][ch * 32 + g * 8], vh, vl);
        #pragma unroll
        for (int qt = 0; qt < 2; ++qt) {
          oacc[qt][dh] = __builtin_amdgcn_mfma_f32_16x16x32_f16(pah[qt], vh, oacc[qt][dh], 0, 0, 0);
          oacc[qt][dh] = __builtin_amdgcn_mfma_f32_16x16x32_f16(pah[qt], vl, oacc[qt][dh], 0, 0, 0);
          oacc[qt][dh] = __builtin_amdgcn_mfma_f32_16x16x32_f16(pal[qt], vh, oacc[qt][dh], 0, 0, 0);
        }
      }
    }
  }

  // epilogue
  #pragma unroll
  for (int qt = 0; qt < 2; ++qt)
    #pragma unroll
    for (int r = 0; r < 4; ++r) {
      float inv = 1.0f / lrow[qt][r];
      int row = q0 + wave * 32 + qt * 16 + g * 4 + r;
      #pragma unroll
      for (int dh = 0; dh < 2; ++dh)
        O[(tbase + row) * 256 + h * 32 + dh * 16 + c] = oacc[qt][dh][r] * inv;
    }
}

// ---------------- Old fp32 attention (fallback path) ------------------------
__global__ __launch_bounds__(256) void attn_kernel(
    const float* __restrict__ qkv, float* __restrict__ O)
{
  const int tid = threadIdx.x;
  const int wave = tid >> 6, lane = tid & 63;
  const int bh = blockIdx.y, b = bh >> 3, h = bh & 7;
  const int q0 = blockIdx.x * 8;
  const size_t tbase = (size_t)b * 2048;
  const float SCALE = 0.17677669529663687f;

  __shared__ float Ks[64][36];
  __shared__ float Vt[32][68];
  __shared__ float Ps[4][2][64];

  const int wq = __builtin_amdgcn_readfirstlane(wave);
  const float* qr0 = qkv + (tbase + q0 + wq * 2) * 768 + h * 32;
  float qa[32], qb[32];
  #pragma unroll
  for (int i = 0; i < 32; ++i) { qa[i] = qr0[i]; qb[i] = qr0[768 + i]; }

  const int r = lane >> 5, d = lane & 31;
  float m0 = -INFINITY, m1 = -INFINITY, l0 = 0.f, l1 = 0.f, oacc = 0.f;

  for (int k0 = 0; k0 < 2048; k0 += 64) {
    __syncthreads();
    {
      int j = tid >> 2;
      int c = (tid & 3) * 8;
      const float* kp = qkv + (tbase + k0 + j) * 768 + 256 + h * 32 + c;
      float4 ka = *reinterpret_cast<const float4*>(kp);
      float4 kb = *reinterpret_cast<const float4*>(kp + 4);
      *reinterpret_cast<float4*>(&Ks[j][c]) = ka;
      *reinterpret_cast<float4*>(&Ks[j][c + 4]) = kb;
      const float* vp = qkv + (tbase + k0 + j) * 768 + 512 + h * 32 + c;
      float4 va = *reinterpret_cast<const float4*>(vp);
      float4 vb = *reinterpret_cast<const float4*>(vp + 4);
      Vt[c + 0][j] = va.x; Vt[c + 1][j] = va.y; Vt[c + 2][j] = va.z; Vt[c + 3][j] = va.w;
      Vt[c + 4][j] = vb.x; Vt[c + 5][j] = vb.y; Vt[c + 6][j] = vb.z; Vt[c + 7][j] = vb.w;
    }
    __syncthreads();
    float s0 = 0.f, s1 = 0.f;
    #pragma unroll
    for (int dd = 0; dd < 8; ++dd) {
      float4 kv = *reinterpret_cast<const float4*>(&Ks[lane][dd * 4]);
      s0 = fmaf(qa[dd * 4 + 0], kv.x, s0); s1 = fmaf(qb[dd * 4 + 0], kv.x, s1);
      s0 = fmaf(qa[dd * 4 + 1], kv.y, s0); s1 = fmaf(qb[dd * 4 + 1], kv.y, s1);
      s0 = fmaf(qa[dd * 4 + 2], kv.z, s0); s1 = fmaf(qb[dd * 4 + 2], kv.z, s1);
      s0 = fmaf(qa[dd * 4 + 3], kv.w, s0); s1 = fmaf(qb[dd * 4 + 3], kv.w, s1);
    }
    s0 *= SCALE; s1 *= SCALE;
    float mx0 = s0, mx1 = s1;
    #pragma unroll
    for (int off = 32; off; off >>= 1) {
      mx0 = fmaxf(mx0, __shfl_xor(mx0, off));
      mx1 = fmaxf(mx1, __shfl_xor(mx1, off));
    }
    float nm0 = fmaxf(m0, mx0), nm1 = fmaxf(m1, mx1);
    float p0 = expf(s0 - nm0), p1 = expf(s1 - nm1);
    float a0 = expf(m0 - nm0), a1 = expf(m1 - nm1);
    float sp0 = p0, sp1 = p1;
    #pragma unroll
    for (int off = 32; off; off >>= 1) {
      sp0 += __shfl_xor(sp0, off);
      sp1 += __shfl_xor(sp1, off);
    }
    l0 = l0 * a0 + sp0; l1 = l1 * a1 + sp1;
    m0 = nm0; m1 = nm1;
    Ps[wave][0][lane] = p0; Ps[wave][1][lane] = p1;
    oacc *= (r == 0) ? a0 : a1;
    #pragma unroll
    for (int jq = 0; jq < 16; ++jq) {
      float4 pv = *reinterpret_cast<const float4*>(&Ps[wave][r][jq * 4]);
      float4 vv = *reinterpret_cast<const float4*>(&Vt[d][jq * 4]);
      oacc = fmaf(pv.x, vv.x, oacc);
      oacc = fmaf(pv.y, vv.y, oacc);
      oacc = fmaf(pv.z, vv.z, oacc);
      oacc = fmaf(pv.w, vv.w, oacc);
    }
  }
  float lf = (r == 0) ? l0 : l1;
  oacc /= lf;
  O[(tbase + q0 + wave * 2 + r) * 256 + h * 32 + d] = oacc;
}

// ---------------- launch --------------------------------------------------
extern "C" void kernel_launch(void* const* d_in, const int* in_sizes, int n_in,
                              void* d_out, int out_size, void* d_ws, size_t ws_size,
                              hipStream_t stream) {
  const float* x       = (const float*)d_in[0];
  const float* q_in    = (const float*)d_in[1];
  const float* q_proc  = (const float*)d_in[2];
  const float* k_in    = (const float*)d_in[3];
  const float* k_proc  = (const float*)d_in[4];
  const float* v_in    = (const float*)d_in[5];
  const float* v_proc  = (const float*)d_in[6];
  const float* o_proc  = (const float*)d_in[7];
  const float* o_out   = (const float*)d_in[8];
  const float* rd_in   = (const float*)d_in[9];
  const float* rd_proc = (const float*)d_in[10];
  const float* ru_out  = (const float*)d_in[11];
  const float* ru_proc = (const float*)d_in[12];
  float* out = (float*)d_out;
  float* qkv = (float*)d_out;   // [8192,768] fp32 in d_out[0,24MB); dead before final GEMM

  const size_t NEED2 = (768ull << 10) + 768ull * 8192 * 2 * 2 + 8192ull * 1024 * 2 * 2;  // ~59.5MB

  if (ws_size >= NEED2) {
    char* wsb = (char*)d_ws;
    float* iw    = (float*)wsb;                 // 256KB
    float* owt   = (float*)(wsb + (256 << 10)); // 256KB
    int*   pidx  = (int*)(wsb + (512 << 10));   // 128KB
    int*   pidxu = (int*)(wsb + (640 << 10));   // 128KB
    char*  R1    = wsb + (768 << 10);           // packed B for QKV: 25.17MB
    f16* bth_q = (f16*)R1;
    f16* btl_q = (f16*)(R1 + 768ull * 8192 * 2);
    char*  R2    = R1 + 768ull * 8192 * 2 * 2;  // 33.55MB region
    // phase 1 (QKV gemm): Xh/Xl fill all of R2
    f16* Xh = (f16*)R2;
    f16* Xl = (f16*)(R2 + 8192ull * 1024 * 2);
    // R2 reuse after QKV gemm:
    float* obuf  = (float*)R2;                              //  8.39MB
    f16* Oh    = (f16*)(R2 + 8388608);                      //  4.19MB
    f16* Ol    = (f16*)(R2 + 12582912);                     //  4.19MB
    f16* bth_o = (f16*)(R2 + 16777216);                     //  4.19MB
    f16* btl_o = (f16*)(R2 + 20971520);                     //  4.19MB
    // V packed plane in d_out tail [24MB, 32MB): exactly 8.39MB, dead after attn
    unsigned int* Vpk = (unsigned int*)((char*)d_out + 25165824);

    // down-router + fused X hi/lo split
    router_v2<4><<<dim3(512), dim3(256), 0, stream>>>(x, rd_in, rd_proc, iw, pidx, Xh, Xl);
    pack_bt<<<dim3(128, 4), dim3(256), 0, stream>>>(q_in, bth_q,                 btl_q,                 256, 8192);
    pack_bt<<<dim3(128, 4), dim3(256), 0, stream>>>(k_in, bth_q + 256ull * 8192, btl_q + 256ull * 8192, 256, 8192);
    pack_bt<<<dim3(128, 4), dim3(256), 0, stream>>>(v_in, bth_q + 512ull * 8192, btl_q + 512ull * 8192, 256, 8192);
    // QKV mixture GEMM: 128x96 tile -> 64x8 = 512 blocks (measured-best NFRAG=3)
    gemm_split2<3><<<dim3(64, 8), dim3(256), 0, stream>>>(Xh, Xl, 1024, iw, bth_q, btl_q,
                                                          qkv, 768, 8192);
    // Householder; V circuit emits packed u32 plane for attention
    hh_kernel<<<dim3(2048, 3), dim3(256), 0, stream>>>(qkv, 768, q_proc, k_proc, v_proc, pidx,
                                                       Vpk);
    pack_bt<<<dim3(32, 16), dim3(256), 0, stream>>>(o_out, bth_o, btl_o, 1024, 2048);
    // attention: packed-u32 LDS, V pre-packed, T14 register prefetch
    attn_mfma<<<dim3(16, 32), dim3(256), 0, stream>>>(qkv, Vpk, obuf);
    // fused up-router + Householder-up + O hi/lo split
    router_hh_up<<<dim3(512), dim3(256), 0, stream>>>(obuf, ru_out, ru_proc, o_proc,
                                                      owt, pidxu, Oh, Ol);
    // output mixture GEMM: 128x128 tile -> 64x8 = 512 blocks (measured-best NFRAG=4)
    gemm_split2<4><<<dim3(64, 8), dim3(256), 0, stream>>>(Oh, Ol, 256, owt, bth_o, btl_o,
                                                          out, 1024, 2048);
  } else {
    // fp32 fallback (fits small ws)
    float* ws = (float*)d_ws;
    float* iw    = ws;
    int*   pidx  = (int*)(ws + 65536);
    float* obuf  = ws + 65536 + 24576;
    float* owt   = obuf + 8192 * 256;
    int*   pidxu = (int*)(owt + 65536);

    router_v2<4><<<dim3(512), dim3(256), 0, stream>>>(x, rd_in, rd_proc, iw, pidx,
                                                      (f16*)nullptr, (f16*)nullptr);
    gemm_mix<<<dim3(64, 2, 3), dim3(256), 0, stream>>>(x, 1024, iw, q_in, k_in, v_in,
                                                       256, qkv, 768, 256);
    hh_kernel<<<dim3(2048, 3), dim3(256), 0, stream>>>(qkv, 768, q_proc, k_proc, v_proc, pidx,
                                                       (unsigned int*)nullptr);
    attn_kernel<<<dim3(256, 32), dim3(256), 0, stream>>>(qkv, obuf);
    router_v2<1><<<dim3(512), dim3(256), 0, stream>>>(obuf, ru_out, ru_proc, owt, pidxu,
                                                      (f16*)nullptr, (f16*)nullptr);
    hh_kernel<<<dim3(2048, 1), dim3(256), 0, stream>>>(obuf, 256, o_proc, o_proc, o_proc, pidxu,
                                                       (unsigned int*)nullptr);
    gemm_mix<<<dim3(64, 8, 1), dim3(256), 0, stream>>>(obuf, 256, owt, o_out, o_out, o_out,
                                                       1024, out, 1024, 1024);
  }
}

// Round 11
// 701.402 us; speedup vs baseline: 1.0621x; 1.0398x over previous
//
#include <hip/hip_runtime.h>
#include <math.h>

// Problem constants
#define NI 8
#define NP 32
#define TOPK 3

typedef _Float16 f16;
typedef f16 f16x8 __attribute__((ext_vector_type(8)));
typedef f16 f16x4 __attribute__((ext_vector_type(4)));
typedef float f32x4 __attribute__((ext_vector_type(4)));

__device__ __forceinline__ float wave_sum(float v) {
  #pragma unroll
  for (int off = 32; off; off >>= 1) v += __shfl_xor(v, off);
  return v;
}

// async 16B global -> LDS (dest = wave-uniform base + lane*16)
__device__ __forceinline__ void gload16(const void* g, void* l) {
  __builtin_amdgcn_global_load_lds(
      (const __attribute__((address_space(1))) unsigned int*)g,
      (__attribute__((address_space(3))) unsigned int*)l, 16, 0, 0);
}

__device__ __forceinline__ void split4(float4 v, f16x4& h, f16x4& l) {
  h[0] = (f16)v.x; l[0] = (f16)(v.x - (float)h[0]);
  h[1] = (f16)v.y; l[1] = (f16)(v.y - (float)h[1]);
  h[2] = (f16)v.z; l[2] = (f16)(v.z - (float)h[2]);
  h[3] = (f16)v.w; l[3] = (f16)(v.w - (float)h[3]);
}

// pack one fp32 into (hi f16 | lo f16 << 16)
__device__ __forceinline__ unsigned int pack_f16x2(float x) {
  f16 h = (f16)x;
  f16 l = (f16)(x - (float)h);
  return (unsigned int)__builtin_bit_cast(unsigned short, h)
       | ((unsigned int)__builtin_bit_cast(unsigned short, l) << 16);
}

// read 8 packed u32 from LDS -> hi f16x8, lo f16x8
__device__ __forceinline__ void unpack8(const unsigned int* p, f16x8& hi, f16x8& lo) {
  uint4 w0 = *reinterpret_cast<const uint4*>(p);
  uint4 w1 = *reinterpret_cast<const uint4*>(p + 4);
  union { unsigned int u[4]; f16x8 v; } H, L;
  H.u[0] = (w0.x & 0xffffu) | (w0.y << 16);
  L.u[0] = (w0.x >> 16)     | (w0.y & 0xffff0000u);
  H.u[1] = (w0.z & 0xffffu) | (w0.w << 16);
  L.u[1] = (w0.z >> 16)     | (w0.w & 0xffff0000u);
  H.u[2] = (w1.x & 0xffffu) | (w1.y << 16);
  L.u[2] = (w1.x >> 16)     | (w1.y & 0xffff0000u);
  H.u[3] = (w1.z & 0xffffu) | (w1.w << 16);
  L.u[3] = (w1.z >> 16)     | (w1.w & 0xffff0000u);
  hi = H.v; lo = L.v;
}

// ---------------- Router v2: 4 tokens per wave in registers -----------------
template<int CHUNKS>  // Kin = CHUNKS*256
__global__ __launch_bounds__(256) void router_v2(
    const float* __restrict__ X,
    const float* __restrict__ Wsm,   // [8, Kin]
    const float* __restrict__ Wtk,   // [32, Kin]
    float* __restrict__ iw, int* __restrict__ pidx,
    f16* __restrict__ Xh, f16* __restrict__ Xl)
{
  const int Kin = CHUNKS * 256;
  const int tid = threadIdx.x, wave = tid >> 6, lane = tid & 63;
  __shared__ float sc[4][4][40];
  const size_t t0 = (size_t)blockIdx.x * 16 + wave * 4;

  float4 xv[4][CHUNKS];
  #pragma unroll
  for (int tt = 0; tt < 4; ++tt) {
    const float4* Xp = reinterpret_cast<const float4*>(X + (t0 + tt) * Kin);
    #pragma unroll
    for (int c = 0; c < CHUNKS; ++c) xv[tt][c] = Xp[c * 64 + lane];
  }
  if (Xh) {  // fused split-write
    #pragma unroll
    for (int tt = 0; tt < 4; ++tt)
      #pragma unroll
      for (int c = 0; c < CHUNKS; ++c) {
        f16x4 h, l;
        split4(xv[tt][c], h, l);
        size_t off = (t0 + tt) * Kin + (c * 64 + lane) * 4;
        *reinterpret_cast<f16x4*>(Xh + off) = h;
        *reinterpret_cast<f16x4*>(Xl + off) = l;
      }
  }

  for (int w = 0; w < 40; ++w) {
    const float* Wr = (w < NI) ? (Wsm + (size_t)w * Kin) : (Wtk + (size_t)(w - NI) * Kin);
    const float4* Wp = reinterpret_cast<const float4*>(Wr);
    float p[4] = {};
    #pragma unroll
    for (int c = 0; c < CHUNKS; ++c) {
      float4 wv = Wp[c * 64 + lane];
      #pragma unroll
      for (int tt = 0; tt < 4; ++tt) {
        p[tt] = fmaf(xv[tt][c].x, wv.x, p[tt]);
        p[tt] = fmaf(xv[tt][c].y, wv.y, p[tt]);
        p[tt] = fmaf(xv[tt][c].z, wv.z, p[tt]);
        p[tt] = fmaf(xv[tt][c].w, wv.w, p[tt]);
      }
    }
    #pragma unroll
    for (int tt = 0; tt < 4; ++tt) {
      p[tt] = wave_sum(p[tt]);
      if (lane == 0) sc[wave][tt][w] = p[tt];
    }
  }

  for (int tt = 0; tt < 4; ++tt) {
    float s = (lane < NI) ? sc[wave][tt][lane] : -3.0e38f;
    float m = s;
    #pragma unroll
    for (int off = 4; off; off >>= 1) m = fmaxf(m, __shfl_xor(m, off));
    float e = expf(s - m);
    float sum = e;
    #pragma unroll
    for (int off = 4; off; off >>= 1) sum += __shfl_xor(sum, off);
    if (lane < NI) iw[(t0 + tt) * NI + lane] = e / sum;

    float v = (lane < NP) ? sc[wave][tt][NI + lane] : -3.0e38f;
    int idx = lane;
    #pragma unroll
    for (int j = 0; j < TOPK; ++j) {
      float bv = v; int bi = idx;
      #pragma unroll
      for (int off = 32; off; off >>= 1) {
        float ov = __shfl_xor(bv, off); int oi = __shfl_xor(bi, off);
        if (ov > bv || (ov == bv && oi < bi)) { bv = ov; bi = oi; }
      }
      if (lane == 0) pidx[(t0 + tt) * TOPK + j] = bi;
      if (idx == bi) v = -3.0e38f;
    }
  }
}

// ---------------- Fused up-router + Householder-up + O hi/lo split ----------
__global__ __launch_bounds__(256) void router_hh_up(
    const float* __restrict__ O,
    const float* __restrict__ Wsm,   // ru_out  [8, 256]
    const float* __restrict__ Wtk,   // ru_proc [32, 256]
    const float* __restrict__ Pm,    // o_proc  [32, 256]
    float* __restrict__ owt, int* __restrict__ pidxu,
    f16* __restrict__ Oh, f16* __restrict__ Ol)
{
  const int tid = threadIdx.x, wave = tid >> 6, lane = tid & 63;
  __shared__ float sc[4][4][40];
  const size_t t0 = (size_t)blockIdx.x * 16 + wave * 4;

  float4 xv[4];
  #pragma unroll
  for (int tt = 0; tt < 4; ++tt)
    xv[tt] = *reinterpret_cast<const float4*>(O + (t0 + tt) * 256 + lane * 4);

  for (int w = 0; w < 40; ++w) {
    const float* Wr = (w < NI) ? (Wsm + (size_t)w * 256) : (Wtk + (size_t)(w - NI) * 256);
    float4 wv = *reinterpret_cast<const float4*>(Wr + lane * 4);
    float p[4];
    #pragma unroll
    for (int tt = 0; tt < 4; ++tt) {
      float q = 0.f;
      q = fmaf(xv[tt].x, wv.x, q); q = fmaf(xv[tt].y, wv.y, q);
      q = fmaf(xv[tt].z, wv.z, q); q = fmaf(xv[tt].w, wv.w, q);
      p[tt] = wave_sum(q);
    }
    #pragma unroll
    for (int tt = 0; tt < 4; ++tt)
      if (lane == 0) sc[wave][tt][w] = p[tt];
  }

  for (int tt = 0; tt < 4; ++tt) {
    float s = (lane < NI) ? sc[wave][tt][lane] : -3.0e38f;
    float m = s;
    #pragma unroll
    for (int off = 4; off; off >>= 1) m = fmaxf(m, __shfl_xor(m, off));
    float e = expf(s - m);
    float sum = e;
    #pragma unroll
    for (int off = 4; off; off >>= 1) sum += __shfl_xor(sum, off);
    if (lane < NI) owt[(t0 + tt) * NI + lane] = e / sum;

    float v = (lane < NP) ? sc[wave][tt][NI + lane] : -3.0e38f;
    int idx = lane;
    int pid[TOPK];
    #pragma unroll
    for (int j = 0; j < TOPK; ++j) {
      float bv = v; int bi = idx;
      #pragma unroll
      for (int off = 32; off; off >>= 1) {
        float ov = __shfl_xor(bv, off); int oi = __shfl_xor(bi, off);
        if (ov > bv || (ov == bv && oi < bi)) { bv = ov; bi = oi; }
      }
      pid[j] = bi;
      if (lane == 0) pidxu[(t0 + tt) * TOPK + j] = bi;
      if (idx == bi) v = -3.0e38f;
    }

    float4 x4 = xv[tt];
    #pragma unroll
    for (int j = 0; j < TOPK; ++j) {
      const float* vp = Pm + (size_t)pid[j] * 256;
      float4 v4 = *reinterpret_cast<const float4*>(vp + lane * 4);
      float ss = v4.x * v4.x + v4.y * v4.y + v4.z * v4.z + v4.w * v4.w;
      ss = wave_sum(ss);
      float inv = 1.0f / sqrtf(ss + 1e-8f);
      float4 vn = {v4.x * inv, v4.y * inv, v4.z * inv, v4.w * inv};
      float dt = vn.x * x4.x + vn.y * x4.y + vn.z * x4.z + vn.w * x4.w;
      dt = wave_sum(dt);
      float d2 = 2.0f * dt;
      x4.x = fmaf(-d2, vn.x, x4.x);
      x4.y = fmaf(-d2, vn.y, x4.y);
      x4.z = fmaf(-d2, vn.z, x4.z);
      x4.w = fmaf(-d2, vn.w, x4.w);
    }
    f16x4 h, l;
    split4(x4, h, l);
    *reinterpret_cast<f16x4*>(Oh + (t0 + tt) * 256 + lane * 4) = h;
    *reinterpret_cast<f16x4*>(Ol + (t0 + tt) * 256 + lane * 4) = l;
  }
}

// ---------------- Pack B: [K][C] fp32 -> [C][K] fp16 hi/lo (transpose+split)
__global__ __launch_bounds__(256) void pack_bt(
    const float* __restrict__ S, f16* __restrict__ Dh, f16* __restrict__ Dl,
    int C, int K)
{
  __shared__ float T[64][65];
  const int tid = threadIdx.x;
  const int kb = blockIdx.x * 64, cb = blockIdx.y * 64;
  const int tr = tid >> 4, tc = (tid & 15) * 4;
  #pragma unroll
  for (int i = 0; i < 4; ++i) {
    float4 v = *reinterpret_cast<const float4*>(&S[(size_t)(kb + tr + i * 16) * C + cb + tc]);
    T[tr + i * 16][tc + 0] = v.x; T[tr + i * 16][tc + 1] = v.y;
    T[tr + i * 16][tc + 2] = v.z; T[tr + i * 16][tc + 3] = v.w;
  }
  __syncthreads();
  #pragma unroll
  for (int i = 0; i < 4; ++i) {
    int c = tr + i * 16;
    f16x4 vh, vl;
    #pragma unroll
    for (int q = 0; q < 4; ++q) {
      float a = T[tc + q][c];
      f16 h = (f16)a;
      vh[q] = h;
      vl[q] = (f16)(a - (float)h);
    }
    *reinterpret_cast<f16x4*>(&Dh[(size_t)(cb + c) * K + kb + tc]) = vh;
    *reinterpret_cast<f16x4*>(&Dl[(size_t)(cb + c) * K + kb + tc]) = vl;
  }
}

// ---------------- Split-f16 MFMA mixture GEMM, TBK=64 (QKV) -----------------
// Tile 128x64, 4 waves 2x2 (wave tile 64x32), TBK=64 -> 48 MFMA/barrier,
// 52KB LDS -> 3 blocks/CU. 8 slots/row, slot' = ((idx>>1)+kseg)&7.
__global__ __launch_bounds__(256, 3) void gemm_k64(
    const f16* __restrict__ Xh, const f16* __restrict__ Xl, int Kin,
    const float* __restrict__ W,                               // [T, 8]
    const f16* __restrict__ Bth, const f16* __restrict__ Btl,  // [N][Ktot]
    float* __restrict__ C, int ldC, int Ktot)
{
  __shared__ f16x8 AhL[1024];   // 16KB: 128 rows x 8 slots
  __shared__ f16x8 AlL[1024];   // 16KB
  __shared__ f16x8 BhL[512];    //  8KB: 64 cols x 8 slots
  __shared__ f16x8 BlL[512];    //  8KB
  __shared__ float Ws[128][NI]; //  4KB  -> 52KB

  const int tid = threadIdx.x;
  const int wave = tid >> 6, lane = tid & 63;
  const int wm = wave >> 1, wn = wave & 1;
  const int fr = lane & 15, ks = lane >> 4;
  const int row0 = blockIdx.x * 128, c0 = blockIdx.y * 64;

  for (int i = tid; i < 128 * NI; i += 256)
    Ws[i >> 3][i & 7] = W[(size_t)(row0 + (i >> 3)) * NI + (i & 7)];

  // A sources: 4 issues per plane, linear slot s = i*256+tid
  const f16* xhp[4];
  const f16* xlp[4];
  #pragma unroll
  for (int i = 0; i < 4; ++i) {
    int s = i * 256 + tid;
    int r = s >> 3, kg = ((s & 7) - (r >> 1)) & 7;
    xhp[i] = Xh + (size_t)(row0 + r) * Kin + kg * 8;
    xlp[i] = Xl + (size_t)(row0 + r) * Kin + kg * 8;
  }
  // B sources: 2 issues per plane
  const f16* bhp[2];
  const f16* blp[2];
  #pragma unroll
  for (int i = 0; i < 2; ++i) {
    int s = i * 256 + tid;
    int cc = s >> 3, kg = ((s & 7) - (cc >> 1)) & 7;
    bhp[i] = Bth + (size_t)(c0 + cc) * Ktot + kg * 8;
    blp[i] = Btl + (size_t)(c0 + cc) * Ktot + kg * 8;
  }

  f32x4 acc[4][2] = {};
  f32x4 cac[4][2] = {};

  int n = 0, dk0 = 0;
  for (int kt = 0; kt < Ktot; kt += 64) {
    __syncthreads();
    #pragma unroll
    for (int i = 0; i < 4; ++i) {
      gload16(xhp[i] + dk0, &AhL[i * 256 + wave * 64]);
      gload16(xlp[i] + dk0, &AlL[i * 256 + wave * 64]);
    }
    #pragma unroll
    for (int i = 0; i < 2; ++i) {
      gload16(bhp[i] + kt, &BhL[i * 256 + wave * 64]);
      gload16(blp[i] + kt, &BlL[i * 256 + wave * 64]);
    }
    __syncthreads();

    #pragma unroll
    for (int kk = 0; kk < 2; ++kk) {
      f16x8 ah[4], al[4], bh[2], bl[2];
      #pragma unroll
      for (int mf = 0; mf < 4; ++mf) {
        int ar = wm * 64 + mf * 16 + fr;
        int sl = ar * 8 + (((ar >> 1) + kk * 4 + ks) & 7);
        ah[mf] = AhL[sl]; al[mf] = AlL[sl];
      }
      #pragma unroll
      for (int nf = 0; nf < 2; ++nf) {
        int bc = wn * 32 + nf * 16 + fr;
        int sl = bc * 8 + (((bc >> 1) + kk * 4 + ks) & 7);
        bh[nf] = BhL[sl]; bl[nf] = BlL[sl];
      }
      #pragma unroll
      for (int mf = 0; mf < 4; ++mf)
        #pragma unroll
        for (int nf = 0; nf < 2; ++nf) {
          acc[mf][nf] = __builtin_amdgcn_mfma_f32_16x16x32_f16(ah[mf], bh[nf], acc[mf][nf], 0, 0, 0);
          acc[mf][nf] = __builtin_amdgcn_mfma_f32_16x16x32_f16(ah[mf], bl[nf], acc[mf][nf], 0, 0, 0);
          acc[mf][nf] = __builtin_amdgcn_mfma_f32_16x16x32_f16(al[mf], bh[nf], acc[mf][nf], 0, 0, 0);
        }
    }

    dk0 += 64;
    if (dk0 == Kin) {   // n-pass boundary: fold iw_n into cac, reset acc
      dk0 = 0;
      #pragma unroll
      for (int mf = 0; mf < 4; ++mf) {
        float w0 = Ws[wm * 64 + mf * 16 + ks * 4 + 0][n];
        float w1 = Ws[wm * 64 + mf * 16 + ks * 4 + 1][n];
        float w2 = Ws[wm * 64 + mf * 16 + ks * 4 + 2][n];
        float w3 = Ws[wm * 64 + mf * 16 + ks * 4 + 3][n];
        #pragma unroll
        for (int nf = 0; nf < 2; ++nf) {
          cac[mf][nf][0] = fmaf(w0, acc[mf][nf][0], cac[mf][nf][0]);
          cac[mf][nf][1] = fmaf(w1, acc[mf][nf][1], cac[mf][nf][1]);
          cac[mf][nf][2] = fmaf(w2, acc[mf][nf][2], cac[mf][nf][2]);
          cac[mf][nf][3] = fmaf(w3, acc[mf][nf][3], cac[mf][nf][3]);
          acc[mf][nf] = (f32x4){0.f, 0.f, 0.f, 0.f};
        }
      }
      ++n;
    }
  }

  #pragma unroll
  for (int mf = 0; mf < 4; ++mf)
    #pragma unroll
    for (int nf = 0; nf < 2; ++nf) {
      int col = c0 + wn * 32 + nf * 16 + fr;
      #pragma unroll
      for (int j = 0; j < 4; ++j) {
        int row = row0 + wm * 64 + mf * 16 + ks * 4 + j;
        C[(size_t)row * ldC + col] = cac[mf][nf][j];
      }
    }
}

// ---------------- Split-f16 MFMA mixture GEMM (single-buffer, TBK=32) -------
#define TBM 128
#define TBK 32

template<int NFRAG>   // 2 -> TBN=64 (out-proj)
__global__ __launch_bounds__(256, 3) void gemm_split2(
    const f16* __restrict__ Xh, const f16* __restrict__ Xl, int Kin,
    const float* __restrict__ W,                               // [T, 8]
    const f16* __restrict__ Bth, const f16* __restrict__ Btl,  // [N][Ktot]
    float* __restrict__ C, int ldC, int Ktot)
{
  const int TBN = 32 * NFRAG;
  __shared__ f16x8 AhL[512];
  __shared__ f16x8 AlL[512];
  __shared__ f16x8 BhL[TBN * 4];
  __shared__ f16x8 BlL[TBN * 4];
  __shared__ float Ws[TBM][NI];

  const int tid = threadIdx.x;
  const int wave = tid >> 6, lane = tid & 63;
  const int wm = wave >> 1, wn = wave & 1;
  const int fr = lane & 15, ks = lane >> 4;
  const int row0 = blockIdx.x * TBM, c0 = blockIdx.y * TBN;

  for (int i = tid; i < TBM * NI; i += 256)
    Ws[i >> 3][i & 7] = W[(size_t)(row0 + (i >> 3)) * NI + (i & 7)];

  const int s1 = 256 + tid;
  const int ar0 = tid >> 2, kg0 = ((tid & 3) - (ar0 >> 1)) & 3;
  const int ar1 = s1 >> 2,  kg1 = ((s1 & 3) - (ar1 >> 1)) & 3;

  const f16* xh0 = Xh + (size_t)(row0 + ar0) * Kin + kg0 * 8;
  const f16* xh1 = Xh + (size_t)(row0 + ar1) * Kin + kg1 * 8;
  const f16* xl0 = Xl + (size_t)(row0 + ar0) * Kin + kg0 * 8;
  const f16* xl1 = Xl + (size_t)(row0 + ar1) * Kin + kg1 * 8;
  const f16* bh0 = Bth + (size_t)(c0 + ar0) * Ktot + kg0 * 8;
  const f16* bl0 = Btl + (size_t)(c0 + ar0) * Ktot + kg0 * 8;
  const int ar1b = (ar1 < TBN) ? ar1 : 0;
  const f16* bh1 = Bth + (size_t)(c0 + ar1b) * Ktot + kg1 * 8;
  const f16* bl1 = Btl + (size_t)(c0 + ar1b) * Ktot + kg1 * 8;
  const bool b2 = (NFRAG == 4) || (NFRAG == 3 && wave < 2);

  f16x8* AhW = &AhL[wave * 64];
  f16x8* AlW = &AlL[wave * 64];
  f16x8* BhW = &BhL[wave * 64];
  f16x8* BlW = &BlL[wave * 64];

  f32x4 acc[4][NFRAG] = {};
  f32x4 cac[4][NFRAG] = {};

  int n = 0, dk0 = 0;
  for (int kt = 0; kt < Ktot; kt += TBK) {
    __syncthreads();
    gload16(xh0 + dk0, AhW);
    gload16(xh1 + dk0, AhW + 256);
    gload16(xl0 + dk0, AlW);
    gload16(xl1 + dk0, AlW + 256);
    gload16(bh0 + kt, BhW);
    gload16(bl0 + kt, BlW);
    if (b2) {
      gload16(bh1 + kt, BhW + 256);
      gload16(bl1 + kt, BlW + 256);
    }
    __syncthreads();

    f16x8 ah[4], al[4], bh[NFRAG], bl[NFRAG];
    #pragma unroll
    for (int mf = 0; mf < 4; ++mf) {
      int ar = wm * 64 + mf * 16 + fr;
      int sl = ar * 4 + (((ar >> 1) + ks) & 3);
      ah[mf] = AhL[sl]; al[mf] = AlL[sl];
    }
    #pragma unroll
    for (int nf = 0; nf < NFRAG; ++nf) {
      int bc = wn * (16 * NFRAG) + nf * 16 + fr;
      int sl = bc * 4 + (((bc >> 1) + ks) & 3);
      bh[nf] = BhL[sl]; bl[nf] = BlL[sl];
    }
    #pragma unroll
    for (int mf = 0; mf < 4; ++mf)
      #pragma unroll
      for (int nf = 0; nf < NFRAG; ++nf) {
        acc[mf][nf] = __builtin_amdgcn_mfma_f32_16x16x32_f16(ah[mf], bh[nf], acc[mf][nf], 0, 0, 0);
        acc[mf][nf] = __builtin_amdgcn_mfma_f32_16x16x32_f16(ah[mf], bl[nf], acc[mf][nf], 0, 0, 0);
        acc[mf][nf] = __builtin_amdgcn_mfma_f32_16x16x32_f16(al[mf], bh[nf], acc[mf][nf], 0, 0, 0);
      }

    dk0 += TBK;
    if (dk0 == Kin) {
      dk0 = 0;
      #pragma unroll
      for (int mf = 0; mf < 4; ++mf) {
        float w0 = Ws[wm * 64 + mf * 16 + ks * 4 + 0][n];
        float w1 = Ws[wm * 64 + mf * 16 + ks * 4 + 1][n];
        float w2 = Ws[wm * 64 + mf * 16 + ks * 4 + 2][n];
        float w3 = Ws[wm * 64 + mf * 16 + ks * 4 + 3][n];
        #pragma unroll
        for (int nf = 0; nf < NFRAG; ++nf) {
          cac[mf][nf][0] = fmaf(w0, acc[mf][nf][0], cac[mf][nf][0]);
          cac[mf][nf][1] = fmaf(w1, acc[mf][nf][1], cac[mf][nf][1]);
          cac[mf][nf][2] = fmaf(w2, acc[mf][nf][2], cac[mf][nf][2]);
          cac[mf][nf][3] = fmaf(w3, acc[mf][nf][3], cac[mf][nf][3]);
          acc[mf][nf] = (f32x4){0.f, 0.f, 0.f, 0.f};
        }
      }
      ++n;
    }
  }

  #pragma unroll
  for (int mf = 0; mf < 4; ++mf)
    #pragma unroll
    for (int nf = 0; nf < NFRAG; ++nf) {
      int col = c0 + wn * (16 * NFRAG) + nf * 16 + fr;
      #pragma unroll
      for (int j = 0; j < 4; ++j) {
        int row = row0 + wm * 64 + mf * 16 + ks * 4 + j;
        C[(size_t)row * ldC + col] = cac[mf][nf][j];
      }
    }
}

// ---------------- Old fp32 mixture GEMM (fallback if ws tiny) ---------------
#define GBM 128
#define GBN 128
#define GBK 16
#define GBMp 132

__global__ __launch_bounds__(256) void gemm_mix(
    const float* __restrict__ X, int Kin,
    const float* __restrict__ W,
    const float* __restrict__ Bm0, const float* __restrict__ Bm1, const float* __restrict__ Bm2,
    int ldB, float* __restrict__ C, int ldC, int Nz)
{
  __shared__ float As[GBK][GBMp];
  __shared__ float Bs[GBK][GBMp];
  __shared__ float Ws[GBM][NI];
  const int tid = threadIdx.x;
  const int row0 = blockIdx.x * GBM;
  const int z = blockIdx.z;
  const float* Bm = (z == 0) ? Bm0 : (z == 1) ? Bm1 : Bm2;
  const int c0 = blockIdx.y * GBN;
  for (int i = tid; i < GBM * NI; i += 256)
    Ws[i >> 3][i & 7] = W[(size_t)(row0 + (i >> 3)) * NI + (i & 7)];
  __syncthreads();

  float acc[8][8] = {};
  const int tr = tid >> 4, tc = tid & 15;
  const int srow = tid >> 2;
  const int sseg = (tid & 3) * 4;
  const int bk = tid >> 4;
  const int bc = (tid & 15) * 4;

  const int Ktot = Kin * NI;
  int n = 0, dk0 = 0;
  for (int kt = 0; kt < Ktot; kt += GBK) {
    __syncthreads();
    #pragma unroll
    for (int p = 0; p < 2; ++p) {
      int r = p * 64 + srow;
      float4 xv = *reinterpret_cast<const float4*>(&X[(size_t)(row0 + r) * Kin + dk0 + sseg]);
      float wgt = Ws[r][n];
      As[sseg + 0][r] = xv.x * wgt;
      As[sseg + 1][r] = xv.y * wgt;
      As[sseg + 2][r] = xv.z * wgt;
      As[sseg + 3][r] = xv.w * wgt;
    }
    #pragma unroll
    for (int p = 0; p < 2; ++p) {
      int cc = p * 64 + bc;
      float4 bv = *reinterpret_cast<const float4*>(&Bm[(size_t)(kt + bk) * ldB + c0 + cc]);
      *reinterpret_cast<float4*>(&Bs[bk][cc]) = bv;
    }
    __syncthreads();
    #pragma unroll
    for (int k = 0; k < GBK; ++k) {
      float4 a0 = *reinterpret_cast<const float4*>(&As[k][tr * 8]);
      float4 a1 = *reinterpret_cast<const float4*>(&As[k][tr * 8 + 4]);
      float4 b0 = *reinterpret_cast<const float4*>(&Bs[k][tc * 8]);
      float4 b1 = *reinterpret_cast<const float4*>(&Bs[k][tc * 8 + 4]);
      float av[8] = {a0.x, a0.y, a0.z, a0.w, a1.x, a1.y, a1.z, a1.w};
      float bv[8] = {b0.x, b0.y, b0.z, b0.w, b1.x, b1.y, b1.z, b1.w};
      #pragma unroll
      for (int i = 0; i < 8; ++i)
        #pragma unroll
        for (int j = 0; j < 8; ++j)
          acc[i][j] = fmaf(av[i], bv[j], acc[i][j]);
    }
    dk0 += GBK;
    if (dk0 == Kin) { dk0 = 0; ++n; }
  }
  #pragma unroll
  for (int i = 0; i < 8; ++i) {
    int row = row0 + tr * 8 + i;
    float* Cp = C + (size_t)row * ldC + z * Nz + c0 + tc * 8;
    float4 o0 = {acc[i][0], acc[i][1], acc[i][2], acc[i][3]};
    float4 o1 = {acc[i][4], acc[i][5], acc[i][6], acc[i][7]};
    *reinterpret_cast<float4*>(Cp) = o0;
    *reinterpret_cast<float4*>(Cp + 4) = o1;
  }
}

// ---------------- Householder chain (3 reflections) -------------------------
// circ==2 && Vpk: write packed (hi|lo) u32 plane [t][256] (skip fp32 writeback).
__global__ __launch_bounds__(256) void hh_kernel(
    float* __restrict__ X, int ldX,
    const float* __restrict__ P0, const float* __restrict__ P1, const float* __restrict__ P2,
    const int* __restrict__ pidx,
    unsigned int* __restrict__ Vpk)
{
  const int tid = threadIdx.x, wave = tid >> 6, lane = tid & 63;
  const int t = blockIdx.x * 4 + wave;
  const int circ = blockIdx.y;
  const float* P = (circ == 0) ? P0 : (circ == 1) ? P1 : P2;
  float* xp = X + (size_t)t * ldX + circ * 256;
  float4 x4 = *reinterpret_cast<float4*>(xp + lane * 4);
  #pragma unroll
  for (int j = 0; j < TOPK; ++j) {
    int id = pidx[t * TOPK + j];
    const float* vp = P + (size_t)id * 256;
    float4 v4 = *reinterpret_cast<const float4*>(vp + lane * 4);
    float ss = v4.x * v4.x + v4.y * v4.y + v4.z * v4.z + v4.w * v4.w;
    ss = wave_sum(ss);
    float inv = 1.0f / sqrtf(ss + 1e-8f);
    float4 vn = {v4.x * inv, v4.y * inv, v4.z * inv, v4.w * inv};
    float dt = vn.x * x4.x + vn.y * x4.y + vn.z * x4.z + vn.w * x4.w;
    dt = wave_sum(dt);
    float d2 = 2.0f * dt;
    x4.x = fmaf(-d2, vn.x, x4.x);
    x4.y = fmaf(-d2, vn.y, x4.y);
    x4.z = fmaf(-d2, vn.z, x4.z);
    x4.w = fmaf(-d2, vn.w, x4.w);
  }
  if (circ == 2 && Vpk) {
    uint4 pk = {pack_f16x2(x4.x), pack_f16x2(x4.y), pack_f16x2(x4.z), pack_f16x2(x4.w)};
    *reinterpret_cast<uint4*>(Vpk + (size_t)t * 256 + lane * 4) = pk;
  } else {
    *reinterpret_cast<float4*>(xp + lane * 4) = x4;
  }
}

// ---------------- MFMA split-f16 flash attention (packed-u32 LDS) + T14 -----
__global__ __launch_bounds__(256, 2) void attn_mfma(
    const float* __restrict__ qkv, const unsigned int* __restrict__ Vpk,
    float* __restrict__ O)
{
  __shared__ f16 Kh[64][40];            // [kj][d]
  __shared__ f16 Kl[64][40];
  __shared__ unsigned int Vtp[32][68];  // [d][kj], packed hi|lo
  __shared__ unsigned int Pp[4][32][68];// per-wave [qi][kj], packed hi|lo

  const int tid = threadIdx.x, wave = tid >> 6, lane = tid & 63;
  const int c = lane & 15, g = lane >> 4;
  const int bh = blockIdx.y, b = bh >> 3, h = bh & 7;
  const int q0 = blockIdx.x * 128;
  const size_t tbase = (size_t)b * 2048;
  const float SCALE = 0.17677669529663687f;  // 1/sqrt(32)

  f16x8 qh[2], ql[2];
  #pragma unroll
  for (int qt = 0; qt < 2; ++qt) {
    const int row = q0 + wave * 32 + qt * 16 + c;
    const float* qp = qkv + (tbase + row) * 768 + h * 32 + g * 8;
    float4 a = *reinterpret_cast<const float4*>(qp);
    float4 b4 = *reinterpret_cast<const float4*>(qp + 4);
    float qv[8] = {a.x, a.y, a.z, a.w, b4.x, b4.y, b4.z, b4.w};
    #pragma unroll
    for (int j = 0; j < 8; ++j) {
      float xs = qv[j] * SCALE;
      f16 hh = (f16)xs;
      qh[qt][j] = hh;
      ql[qt][j] = (f16)(xs - (float)hh);
    }
  }

  const int kj = tid >> 2, dq = (tid & 3) * 8;
  const int vk = tid & 63, vq = (tid >> 6) * 8;

  float4 rka, rkb;
  uint4 rv0, rv1;
  {
    const float* kp = qkv + (tbase + kj) * 768 + 256 + h * 32 + dq;
    rka = *reinterpret_cast<const float4*>(kp);
    rkb = *reinterpret_cast<const float4*>(kp + 4);
    const unsigned int* vp = Vpk + (tbase + vk) * 256 + h * 32 + vq;
    rv0 = *reinterpret_cast<const uint4*>(vp);
    rv1 = *reinterpret_cast<const uint4*>(vp + 4);
  }

  f32x4 sacc[2][4];
  f32x4 oacc[2][2] = {};
  float mrow[2][4] = {{-INFINITY, -INFINITY, -INFINITY, -INFINITY},
                      {-INFINITY, -INFINITY, -INFINITY, -INFINITY}};
  float lrow[2][4] = {};

  for (int k0 = 0; k0 < 2048; k0 += 64) {
    __syncthreads();
    {
      float kv[8] = {rka.x, rka.y, rka.z, rka.w, rkb.x, rkb.y, rkb.z, rkb.w};
      f16x8 khi, klo;
      #pragma unroll
      for (int j = 0; j < 8; ++j) {
        f16 hh = (f16)kv[j];
        khi[j] = hh;
        klo[j] = (f16)(kv[j] - (float)hh);
      }
      *reinterpret_cast<f16x8*>(&Kh[kj][dq]) = khi;
      *reinterpret_cast<f16x8*>(&Kl[kj][dq]) = klo;

      Vtp[vq + 0][vk] = rv0.x; Vtp[vq + 1][vk] = rv0.y;
      Vtp[vq + 2][vk] = rv0.z; Vtp[vq + 3][vk] = rv0.w;
      Vtp[vq + 4][vk] = rv1.x; Vtp[vq + 5][vk] = rv1.y;
      Vtp[vq + 6][vk] = rv1.z; Vtp[vq + 7][vk] = rv1.w;
    }
    __syncthreads();
    if (k0 + 64 < 2048) {
      const float* kp = qkv + (tbase + k0 + 64 + kj) * 768 + 256 + h * 32 + dq;
      rka = *reinterpret_cast<const float4*>(kp);
      rkb = *reinterpret_cast<const float4*>(kp + 4);
      const unsigned int* vp = Vpk + (tbase + k0 + 64 + vk) * 256 + h * 32 + vq;
      rv0 = *reinterpret_cast<const uint4*>(vp);
      rv1 = *reinterpret_cast<const uint4*>(vp + 4);
    }

    // QK^T
    #pragma unroll
    for (int s = 0; s < 4; ++s) {
      f16x8 kbh = *reinterpret_cast<const f16x8*>(&Kh[s * 16 + c][g * 8]);
      f16x8 kbl = *reinterpret_cast<const f16x8*>(&Kl[s * 16 + c][g * 8]);
      #pragma unroll
      for (int qt = 0; qt < 2; ++qt) {
        f32x4 acc = {0.f, 0.f, 0.f, 0.f};
        acc = __builtin_amdgcn_mfma_f32_16x16x32_f16(qh[qt], kbh, acc, 0, 0, 0);
        acc = __builtin_amdgcn_mfma_f32_16x16x32_f16(qh[qt], kbl, acc, 0, 0, 0);
        acc = __builtin_amdgcn_mfma_f32_16x16x32_f16(ql[qt], kbh, acc, 0, 0, 0);
        sacc[qt][s] = acc;
      }
    }

    // online softmax
    float alpha[2][4];
    #pragma unroll
    for (int qt = 0; qt < 2; ++qt)
      #pragma unroll
      for (int r = 0; r < 4; ++r) {
        float mt = fmaxf(fmaxf(sacc[qt][0][r], sacc[qt][1][r]),
                         fmaxf(sacc[qt][2][r], sacc[qt][3][r]));
        #pragma unroll
        for (int off = 1; off < 16; off <<= 1) mt = fmaxf(mt, __shfl_xor(mt, off));
        float mn = fmaxf(mrow[qt][r], mt);
        float al = __expf(mrow[qt][r] - mn);
        mrow[qt][r] = mn;
        alpha[qt][r] = al;
        float ps = 0.f;
        #pragma unroll
        for (int s = 0; s < 4; ++s) {
          float p = __expf(sacc[qt][s][r] - mn);
          sacc[qt][s][r] = p;
          ps += p;
        }
        #pragma unroll
        for (int off = 1; off < 16; off <<= 1) ps += __shfl_xor(ps, off);
        lrow[qt][r] = lrow[qt][r] * al + ps;
      }

    // write P (packed hi/lo)
    #pragma unroll
    for (int qt = 0; qt < 2; ++qt)
      #pragma unroll
      for (int s = 0; s < 4; ++s)
        #pragma unroll
        for (int r = 0; r < 4; ++r)
          Pp[wave][qt * 16 + g * 4 + r][s * 16 + c] = pack_f16x2(sacc[qt][s][r]);

    // rescale O
    #pragma unroll
    for (int qt = 0; qt < 2; ++qt)
      #pragma unroll
      for (int dh = 0; dh < 2; ++dh)
        #pragma unroll
        for (int r = 0; r < 4; ++r) oacc[qt][dh][r] *= alpha[qt][r];

    // PV
    #pragma unroll
    for (int ch = 0; ch < 2; ++ch) {
      f16x8 pah[2], pal[2];
      #pragma unroll
      for (int qt = 0; qt < 2; ++qt)
        unpack8(&Pp[wave][qt * 16 + c][ch * 32 + g * 8], pah[qt], pal[qt]);
      #pragma unroll
      for (int dh = 0; dh < 2; ++dh) {
        f16x8 vh, vl;
        unpack8(&Vtp[dh * 16 + c][ch * 32 + g * 8], vh, vl);
        #pragma unroll
        for (int qt = 0; qt < 2; ++qt) {
          oacc[qt][dh] = __builtin_amdgcn_mfma_f32_16x16x32_f16(pah[qt], vh, oacc[qt][dh], 0, 0, 0);
          oacc[qt][dh] = __builtin_amdgcn_mfma_f32_16x16x32_f16(pah[qt], vl, oacc[qt][dh], 0, 0, 0);
          oacc[qt][dh] = __builtin_amdgcn_mfma_f32_16x16x32_f16(pal[qt], vh, oacc[qt][dh], 0, 0, 0);
        }
      }
    }
  }

  #pragma unroll
  for (int qt = 0; qt < 2; ++qt)
    #pragma unroll
    for (int r = 0; r < 4; ++r) {
      float inv = 1.0f / lrow[qt][r];
      int row = q0 + wave * 32 + qt * 16 + g * 4 + r;
      #pragma unroll
      for (int dh = 0; dh < 2; ++dh)
        O[(tbase + row) * 256 + h * 32 + dh * 16 + c] = oacc[qt][dh][r] * inv;
    }
}

// ---------------- Old fp32 attention (fallback path) ------------------------
__global__ __launch_bounds__(256) void attn_kernel(
    const float* __restrict__ qkv, float* __restrict__ O)
{
  const int tid = threadIdx.x;
  const int wave = tid >> 6, lane = tid & 63;
  const int bh = blockIdx.y, b = bh >> 3, h = bh & 7;
  const int q0 = blockIdx.x * 8;
  const size_t tbase = (size_t)b * 2048;
  const float SCALE = 0.17677669529663687f;

  __shared__ float Ks[64][36];
  __shared__ float Vt[32][68];
  __shared__ float Ps[4][2][64];

  const int wq = __builtin_amdgcn_readfirstlane(wave);
  const float* qr0 = qkv + (tbase + q0 + wq * 2) * 768 + h * 32;
  float qa[32], qb[32];
  #pragma unroll
  for (int i = 0; i < 32; ++i) { qa[i] = qr0[i]; qb[i] = qr0[768 + i]; }

  const int r = lane >> 5, d = lane & 31;
  float m0 = -INFINITY, m1 = -INFINITY, l0 = 0.f, l1 = 0.f, oacc = 0.f;

  for (int k0 = 0; k0 < 2048; k0 += 64) {
    __syncthreads();
    {
      int j = tid >> 2;
      int c = (tid & 3) * 8;
      const float* kp = qkv + (tbase + k0 + j) * 768 + 256 + h * 32 + c;
      float4 ka = *reinterpret_cast<const float4*>(kp);
      float4 kb = *reinterpret_cast<const float4*>(kp + 4);
      *reinterpret_cast<float4*>(&Ks[j][c]) = ka;
      *reinterpret_cast<float4*>(&Ks[j][c + 4]) = kb;
      const float* vp = qkv + (tbase + k0 + j) * 768 + 512 + h * 32 + c;
      float4 va = *reinterpret_cast<const float4*>(vp);
      float4 vb = *reinterpret_cast<const float4*>(vp + 4);
      Vt[c + 0][j] = va.x; Vt[c + 1][j] = va.y; Vt[c + 2][j] = va.z; Vt[c + 3][j] = va.w;
      Vt[c + 4][j] = vb.x; Vt[c + 5][j] = vb.y; Vt[c + 6][j] = vb.z; Vt[c + 7][j] = vb.w;
    }
    __syncthreads();
    float s0 = 0.f, s1 = 0.f;
    #pragma unroll
    for (int dd = 0; dd < 8; ++dd) {
      float4 kv = *reinterpret_cast<const float4*>(&Ks[lane][dd * 4]);
      s0 = fmaf(qa[dd * 4 + 0], kv.x, s0); s1 = fmaf(qb[dd * 4 + 0], kv.x, s1);
      s0 = fmaf(qa[dd * 4 + 1], kv.y, s0); s1 = fmaf(qb[dd * 4 + 1], kv.y, s1);
      s0 = fmaf(qa[dd * 4 + 2], kv.z, s0); s1 = fmaf(qb[dd * 4 + 2], kv.z, s1);
      s0 = fmaf(qa[dd * 4 + 3], kv.w, s0); s1 = fmaf(qb[dd * 4 + 3], kv.w, s1);
    }
    s0 *= SCALE; s1 *= SCALE;
    float mx0 = s0, mx1 = s1;
    #pragma unroll
    for (int off = 32; off; off >>= 1) {
      mx0 = fmaxf(mx0, __shfl_xor(mx0, off));
      mx1 = fmaxf(mx1, __shfl_xor(mx1, off));
    }
    float nm0 = fmaxf(m0, mx0), nm1 = fmaxf(m1, mx1);
    float p0 = expf(s0 - nm0), p1 = expf(s1 - nm1);
    float a0 = expf(m0 - nm0), a1 = expf(m1 - nm1);
    float sp0 = p0, sp1 = p1;
    #pragma unroll
    for (int off = 32; off; off >>= 1) {
      sp0 += __shfl_xor(sp0, off);
      sp1 += __shfl_xor(sp1, off);
    }
    l0 = l0 * a0 + sp0; l1 = l1 * a1 + sp1;
    m0 = nm0; m1 = nm1;
    Ps[wave][0][lane] = p0; Ps[wave][1][lane] = p1;
    oacc *= (r == 0) ? a0 : a1;
    #pragma unroll
    for (int jq = 0; jq < 16; ++jq) {
      float4 pv = *reinterpret_cast<const float4*>(&Ps[wave][r][jq * 4]);
      float4 vv = *reinterpret_cast<const float4*>(&Vt[d][jq * 4]);
      oacc = fmaf(pv.x, vv.x, oacc);
      oacc = fmaf(pv.y, vv.y, oacc);
      oacc = fmaf(pv.z, vv.z, oacc);
      oacc = fmaf(pv.w, vv.w, oacc);
    }
  }
  float lf = (r == 0) ? l0 : l1;
  oacc /= lf;
  O[(tbase + q0 + wave * 2 + r) * 256 + h * 32 + d] = oacc;
}

// ---------------- launch --------------------------------------------------
extern "C" void kernel_launch(void* const* d_in, const int* in_sizes, int n_in,
                              void* d_out, int out_size, void* d_ws, size_t ws_size,
                              hipStream_t stream) {
  const float* x       = (const float*)d_in[0];
  const float* q_in    = (const float*)d_in[1];
  const float* q_proc  = (const float*)d_in[2];
  const float* k_in    = (const float*)d_in[3];
  const float* k_proc  = (const float*)d_in[4];
  const float* v_in    = (const float*)d_in[5];
  const float* v_proc  = (const float*)d_in[6];
  const float* o_proc  = (const float*)d_in[7];
  const float* o_out   = (const float*)d_in[8];
  const float* rd_in   = (const float*)d_in[9];
  const float* rd_proc = (const float*)d_in[10];
  const float* ru_out  = (const float*)d_in[11];
  const float* ru_proc = (const float*)d_in[12];
  float* out = (float*)d_out;
  float* qkv = (float*)d_out;   // [8192,768] fp32 in d_out[0,24MB); dead before final GEMM

  const size_t NEED2 = (768ull << 10) + 768ull * 8192 * 2 * 2 + 8192ull * 1024 * 2 * 2;  // ~59.5MB

  if (ws_size >= NEED2) {
    char* wsb = (char*)d_ws;
    float* iw    = (float*)wsb;                 // 256KB
    float* owt   = (float*)(wsb + (256 << 10)); // 256KB
    int*   pidx  = (int*)(wsb + (512 << 10));   // 128KB
    int*   pidxu = (int*)(wsb + (640 << 10));   // 128KB
    char*  R1    = wsb + (768 << 10);           // packed B for QKV: 25.17MB
    f16* bth_q = (f16*)R1;
    f16* btl_q = (f16*)(R1 + 768ull * 8192 * 2);
    char*  R2    = R1 + 768ull * 8192 * 2 * 2;  // 33.55MB region
    f16* Xh = (f16*)R2;
    f16* Xl = (f16*)(R2 + 8192ull * 1024 * 2);
    // R2 reuse after QKV gemm:
    float* obuf  = (float*)R2;                              //  8.39MB
    f16* Oh    = (f16*)(R2 + 8388608);                      //  4.19MB
    f16* Ol    = (f16*)(R2 + 12582912);                     //  4.19MB
    f16* bth_o = (f16*)(R2 + 16777216);                     //  4.19MB
    f16* btl_o = (f16*)(R2 + 20971520);                     //  4.19MB
    // V packed plane in d_out tail [24MB, 32MB): exactly 8.39MB, dead after attn
    unsigned int* Vpk = (unsigned int*)((char*)d_out + 25165824);

    // down-router + fused X hi/lo split
    router_v2<4><<<dim3(512), dim3(256), 0, stream>>>(x, rd_in, rd_proc, iw, pidx, Xh, Xl);
    pack_bt<<<dim3(128, 4), dim3(256), 0, stream>>>(q_in, bth_q,                 btl_q,                 256, 8192);
    pack_bt<<<dim3(128, 4), dim3(256), 0, stream>>>(k_in, bth_q + 256ull * 8192, btl_q + 256ull * 8192, 256, 8192);
    pack_bt<<<dim3(128, 4), dim3(256), 0, stream>>>(v_in, bth_q + 512ull * 8192, btl_q + 512ull * 8192, 256, 8192);
    // QKV mixture GEMM: 128x64 tile, TBK=64 -> 64x12 = 768 blocks = 3/CU
    gemm_k64<<<dim3(64, 12), dim3(256), 0, stream>>>(Xh, Xl, 1024, iw, bth_q, btl_q,
                                                     qkv, 768, 8192);
    // Householder; V circuit emits packed u32 plane for attention
    hh_kernel<<<dim3(2048, 3), dim3(256), 0, stream>>>(qkv, 768, q_proc, k_proc, v_proc, pidx,
                                                       Vpk);
    pack_bt<<<dim3(32, 16), dim3(256), 0, stream>>>(o_out, bth_o, btl_o, 1024, 2048);
    // attention: packed-u32 LDS, V pre-packed, T14 register prefetch
    attn_mfma<<<dim3(16, 32), dim3(256), 0, stream>>>(qkv, Vpk, obuf);
    // fused up-router + Householder-up + O hi/lo split
    router_hh_up<<<dim3(512), dim3(256), 0, stream>>>(obuf, ru_out, ru_proc, o_proc,
                                                      owt, pidxu, Oh, Ol);
    // output mixture GEMM: 128x64 tile (NFRAG=2) -> 64x16 = 1024 blocks (R9-best)
    gemm_split2<2><<<dim3(64, 16), dim3(256), 0, stream>>>(Oh, Ol, 256, owt, bth_o, btl_o,
                                                           out, 1024, 2048);
  } else {
    // fp32 fallback (fits small ws)
    float* ws = (float*)d_ws;
    float* iw    = ws;
    int*   pidx  = (int*)(ws + 65536);
    float* obuf  = ws + 65536 + 24576;
    float* owt   = obuf + 8192 * 256;
    int*   pidxu = (int*)(owt + 65536);

    router_v2<4><<<dim3(512), dim3(256), 0, stream>>>(x, rd_in, rd_proc, iw, pidx,
                                                      (f16*)nullptr, (f16*)nullptr);
    gemm_mix<<<dim3(64, 2, 3), dim3(256), 0, stream>>>(x, 1024, iw, q_in, k_in, v_in,
                                                       256, qkv, 768, 256);
    hh_kernel<<<dim3(2048, 3), dim3(256), 0, stream>>>(qkv, 768, q_proc, k_proc, v_proc, pidx,
                                                       (unsigned int*)nullptr);
    attn_kernel<<<dim3(256, 32), dim3(256), 0, stream>>>(qkv, obuf);
    router_v2<1><<<dim3(512), dim3(256), 0, stream>>>(obuf, ru_out, ru_proc, owt, pidxu,
                                                      (f16*)nullptr, (f16*)nullptr);
    hh_kernel<<<dim3(2048, 1), dim3(256), 0, stream>>>(obuf, 256, o_proc, o_proc, o_proc, pidxu,
                                                       (unsigned int*)nullptr);
    gemm_mix<<<dim3(64, 8, 1), dim3(256), 0, stream>>>(obuf, 256, owt, o_out, o_out, o_out,
                                                       1024, out, 1024, 1024);
  }
}